// Round 3
// baseline (1448.721 us; speedup 1.0000x reference)
//
#include <hip/hip_runtime.h>
#include <hip/hip_bf16.h>
#include <math.h>
#include <stdint.h>

// Problem constants
constexpr int N_ROWS = 32768;
constexpr int K_DIM  = 4096;
constexpr int R_DIM  = 256;
constexpr int KP     = 3 * R_DIM;   // 768: split-K' for [hi|hi|lo] x [hi|lo|hi]
constexpr int KB     = K_DIM / 128; // 32 col-blocks in K2 grid

typedef __bf16 bf16x8 __attribute__((ext_vector_type(8)));
typedef float  f32x4  __attribute__((ext_vector_type(4)));
typedef unsigned short u16x8 __attribute__((ext_vector_type(8)));
typedef unsigned short u16x4 __attribute__((ext_vector_type(4)));

// ---- bf16 helpers (round-to-nearest-even; inputs are finite normals) ----
__device__ __forceinline__ unsigned short f2bf(float x) {
    unsigned u = __float_as_uint(x);
    u += 0x7fffu + ((u >> 16) & 1u);
    return (unsigned short)(u >> 16);
}
__device__ __forceinline__ float bf2f(unsigned short h) {
    return __uint_as_float((unsigned)h << 16);
}

// ---- async global->LDS, 16B per lane, LDS dest = wave-uniform base + lane*16
__device__ __forceinline__ void gl2lds16(const void* gptr, void* lptr) {
    __builtin_amdgcn_global_load_lds(
        (const __attribute__((address_space(1))) unsigned int*)gptr,
        (__attribute__((address_space(3))) unsigned int*)lptr,
        16, 0, 0);
}

// ===========================================================================
// K2: M[m,n] = sum_k A[m,k]*B[n,k], bf16 k-major, C fp32. 128x128 tile, BK=32,
// 256 threads = 4 waves (2x2 of 64x64), 16x16x32 MFMA.
// Grid: x = col-panel (32), y = row-panel (256)  -> consecutive blocks share
// the A'-panel; B' (6 MB) is XCD-L2-resident (panel->XCD mapping stationary).
// A' staged via global_load_lds; B' fragments read DIRECTLY from global (L2).
// Epilogue emits per-row softmax partials over this block's 128 cols.
// ===========================================================================
__global__ __launch_bounds__(256)
void gemm_mfma_nt(const unsigned short* __restrict__ A,
                  const unsigned short* __restrict__ B,
                  float* __restrict__ C,
                  float* __restrict__ Pm, float* __restrict__ Ps,
                  int M, int N, int Kc)
{
    __shared__ __align__(16) unsigned short As[128 * 32];
    __shared__ float pm_s[128][2], ps_s[128][2];

    const int tid  = threadIdx.x;
    const int wave = tid >> 6, lane = tid & 63;
    const int wm = wave >> 1, wn = wave & 1;
    const long m0 = (long)blockIdx.y * 128;
    const long n0 = (long)blockIdx.x * 128;

    f32x4 acc[4][4] = {};

    const int srow  = lane >> 2;        // 0..15 within 16-row chunk
    const int skoff = (lane & 3) * 8;   // bf16 elem offset within 32-wide row
    const int c0 = wave, c1 = wave + 4; // each wave stages 2 A-chunks per tile
    const int kq = (lane >> 4) * 8;     // frag k-offset 0,8,16,24
    const int mr = lane & 15;

    const unsigned short* const Bbase = B + n0 * (long)Kc + kq;

    for (int k0 = 0; k0 < Kc; k0 += 32) {
        gl2lds16(A + (m0 + c0 * 16 + srow) * (long)Kc + k0 + skoff, &As[c0 * 512]);
        gl2lds16(A + (m0 + c1 * 16 + srow) * (long)Kc + k0 + skoff, &As[c1 * 512]);

        // B fragments direct from global (L2-resident panel)
        bf16x8 bfr[4];
#pragma unroll
        for (int t = 0; t < 4; ++t)
            bfr[t] = *(const bf16x8*)(Bbase + (wn * 64 + t * 16 + mr) * (long)Kc + k0);

        __syncthreads();

        bf16x8 af[4];
#pragma unroll
        for (int t = 0; t < 4; ++t)
            af[t] = *(const bf16x8*)&As[(wm * 64 + t * 16 + mr) * 32 + kq];
#pragma unroll
        for (int i = 0; i < 4; ++i)
#pragma unroll
            for (int j = 0; j < 4; ++j)
                acc[i][j] = __builtin_amdgcn_mfma_f32_16x16x32_bf16(
                    af[i], bfr[j], acc[i][j], 0, 0, 0);
        __syncthreads();
    }

    // C/D layout: col = lane&15, row = (lane>>4)*4 + reg
    const int col = lane & 15, rquad = (lane >> 4) * 4;
#pragma unroll
    for (int i = 0; i < 4; ++i) {
        const long mrow = m0 + wm * 64 + i * 16 + rquad;
#pragma unroll
        for (int j = 0; j < 4; ++j) {
            float* p = C + mrow * (long)N + n0 + wn * 64 + j * 16 + col;
#pragma unroll
            for (int r = 0; r < 4; ++r) p[(long)r * N] = acc[i][j][r];
        }
    }

    // ---- softmax partials over this block's 128 cols, per row --------------
#pragma unroll
    for (int i = 0; i < 4; ++i) {
#pragma unroll
        for (int r = 0; r < 4; ++r) {
            float mx = fmaxf(fmaxf(acc[i][0][r], acc[i][1][r]),
                             fmaxf(acc[i][2][r], acc[i][3][r]));
#pragma unroll
            for (int off = 1; off < 16; off <<= 1)
                mx = fmaxf(mx, __shfl_xor(mx, off));
            float sm = 0.f;
#pragma unroll
            for (int j = 0; j < 4; ++j) sm += __expf(acc[i][j][r] - mx);
#pragma unroll
            for (int off = 1; off < 16; off <<= 1)
                sm += __shfl_xor(sm, off);
            if (mr == 0) {
                const int rw = wm * 64 + i * 16 + rquad + r;
                pm_s[rw][wn] = mx;
                ps_s[rw][wn] = sm;
            }
        }
    }
    __syncthreads();
    if (tid < 128) {
        const float ma = pm_s[tid][0], mb = pm_s[tid][1];
        const float mx = fmaxf(ma, mb);
        const float s  = ps_s[tid][0] * __expf(ma - mx) +
                         ps_s[tid][1] * __expf(mb - mx);
        Pm[(m0 + tid) * KB + blockIdx.x] = mx;
        Ps[(m0 + tid) * KB + blockIdx.x] = s;
    }
}

// ===========================================================================
// Combine per-block softmax partials -> per-row (max, 1/sum).
// ===========================================================================
__global__ __launch_bounds__(256)
void finalize_ms(const float* __restrict__ Pm, const float* __restrict__ Ps,
                 float* __restrict__ SMm, float* __restrict__ SMi)
{
    const long row = (long)blockIdx.x * 256 + threadIdx.x;
    const float4* pm = (const float4*)(Pm + row * KB);
    const float4* ps = (const float4*)(Ps + row * KB);
    float4 v[8];
    float mx = -3.4e38f;
#pragma unroll
    for (int q = 0; q < 8; ++q) {
        v[q] = pm[q];
        mx = fmaxf(mx, fmaxf(fmaxf(v[q].x, v[q].y), fmaxf(v[q].z, v[q].w)));
    }
    float s = 0.f;
#pragma unroll
    for (int q = 0; q < 8; ++q) {
        float4 w = ps[q];
        s += w.x * __expf(v[q].x - mx) + w.y * __expf(v[q].y - mx) +
             w.z * __expf(v[q].z - mx) + w.w * __expf(v[q].w - mx);
    }
    SMm[row] = mx;
    SMi[row] = 1.f / s;
}

// ===========================================================================
// Single-pass fused softmax-apply + PV:
//   A[n,k] = exp(M[n,k]-m_n) * inv_n   (in place over M)
//   C[n,r] = (sum_k exp(M-m) * LT[r,k]) * inv_n   (bf16 MFMA)
// Grid: N_ROWS/64 blocks x 512 threads (8 waves = 2 row-groups x 4 col-groups).
// BK=64 tiles; As (exp values) double-buffered + XOR-swizzled in LDS;
// LT fragments read directly from global (2 MB, L2-resident).
// One barrier per tile; next tile's M prefetched before current MFMA.
// ===========================================================================
__global__ __launch_bounds__(512)
void softmax_av2(float* __restrict__ Mio,
                 const unsigned short* __restrict__ LT,
                 const float* __restrict__ SMm, const float* __restrict__ SMi,
                 float* __restrict__ C)
{
    __shared__ __align__(16) unsigned short As[2][64 * 64];  // 2 x 8 KiB
    __shared__ float sm_m[64], sm_inv[64];

    const int tid  = threadIdx.x;
    const int wave = tid >> 6, lane = tid & 63;
    const long m0 = (long)blockIdx.x * 64;

    if (tid < 64) { sm_m[tid] = SMm[m0 + tid]; sm_inv[tid] = SMi[m0 + tid]; }
    __syncthreads();

    const int wm = wave >> 2, wn = wave & 3;   // 32 rows x 64 cols per wave
    const int mr = lane & 15;
    const int kq   = (lane >> 4) * 8;          // frag k-offset (elems)
    const int kq16 = (lane >> 4) * 16;         // same in bytes

    // A-emit mapping: thread -> row (0..63), 8 cols starting at (tid&7)*8
    const int arow  = tid >> 3;
    const int abyte = (arow * 128 + (tid & 7) * 16) ^ ((arow & 7) << 4);
    const float myM = sm_m[arow], myI = sm_inv[arow];
    float* const arp = Mio + (m0 + arow) * (long)K_DIM + (tid & 7) * 8;

    const unsigned short* const Lbase = LT + (wn * 64) * (long)K_DIM + kq;

    f32x4 acc[2][4] = {};

    auto emit_A = [&](int buf, int kk0, float4 v0, float4 v1) {
        float e0 = __expf(v0.x - myM), e1 = __expf(v0.y - myM);
        float e2 = __expf(v0.z - myM), e3 = __expf(v0.w - myM);
        float e4 = __expf(v1.x - myM), e5 = __expf(v1.y - myM);
        float e6 = __expf(v1.z - myM), e7 = __expf(v1.w - myM);
        *(float4*)(arp + kk0)     = make_float4(e0*myI, e1*myI, e2*myI, e3*myI);
        *(float4*)(arp + kk0 + 4) = make_float4(e4*myI, e5*myI, e6*myI, e7*myI);
        u16x8 u;
        u[0]=f2bf(e0); u[1]=f2bf(e1); u[2]=f2bf(e2); u[3]=f2bf(e3);
        u[4]=f2bf(e4); u[5]=f2bf(e5); u[6]=f2bf(e6); u[7]=f2bf(e7);
        *(u16x8*)((char*)As[buf] + abyte) = u;
    };

    // prologue: tile 0
    emit_A(0, 0, *(const float4*)arp, *(const float4*)(arp + 4));
    __syncthreads();

    int cur = 0;
    for (int t = 0; t < K_DIM / 64; ++t) {
        const int nxt = cur ^ 1;
        const bool has_next = (t + 1 < K_DIM / 64);
        float4 v0, v1;
        if (has_next) {
            v0 = *(const float4*)(arp + (t + 1) * 64);
            v1 = *(const float4*)(arp + (t + 1) * 64 + 4);
        }

        // LT fragments for this tile, direct from global (L2)
        bf16x8 bfr[2][4];
#pragma unroll
        for (int ks = 0; ks < 2; ++ks)
#pragma unroll
            for (int q = 0; q < 4; ++q)
                bfr[ks][q] = *(const bf16x8*)(Lbase + (q * 16 + mr) * (long)K_DIM
                                              + t * 64 + ks * 32);
        // A fragments from swizzled LDS
        bf16x8 af[2][2];
#pragma unroll
        for (int ks = 0; ks < 2; ++ks)
#pragma unroll
            for (int q = 0; q < 2; ++q) {
                const int ar = wm * 32 + q * 16 + mr;
                af[ks][q] = *(const bf16x8*)((const char*)As[cur] +
                            ((ar * 128 + ks * 64 + kq16) ^ ((ar & 7) << 4)));
            }
#pragma unroll
        for (int ks = 0; ks < 2; ++ks)
#pragma unroll
            for (int i = 0; i < 2; ++i)
#pragma unroll
                for (int j = 0; j < 4; ++j)
                    acc[i][j] = __builtin_amdgcn_mfma_f32_16x16x32_bf16(
                        af[ks][i], bfr[ks][j], acc[i][j], 0, 0, 0);

        if (has_next) emit_A(nxt, (t + 1) * 64, v0, v1);
        __syncthreads();
        cur = nxt;
    }

    // epilogue: scale by 1/s, write C
    const int col = lane & 15, rquad = (lane >> 4) * 4;
#pragma unroll
    for (int i = 0; i < 2; ++i) {
        const int lrow0 = wm * 32 + i * 16 + rquad;
#pragma unroll
        for (int j = 0; j < 4; ++j) {
            float* p = C + (m0 + lrow0) * (long)R_DIM + wn * 64 + j * 16 + col;
#pragma unroll
            for (int r = 0; r < 4; ++r)
                p[(long)r * R_DIM] = acc[i][j][r] * sm_inv[lrow0 + r];
        }
    }
}

// ===========================================================================
// Prep kernels
// ===========================================================================
// B' = [L_hi | L_lo | L_hi]  (K_DIM x 768)
__global__ __launch_bounds__(256)
void prep_B(const float* __restrict__ L, unsigned short* __restrict__ Bp)
{
    const long i = (long)blockIdx.x * 256 + threadIdx.x;   // over K_DIM*R_DIM
    const long k = i >> 8; const int r = (int)(i & 255);
    const float x = L[i];
    const unsigned short hi = f2bf(x);
    const unsigned short lo = f2bf(x - bf2f(hi));
    unsigned short* row = Bp + k * KP;
    row[r] = hi; row[R_DIM + r] = lo; row[2 * R_DIM + r] = hi;
}

// LT[r][k] = bf16(L[k][r])  (256 x 4096) — coalesced writes
__global__ __launch_bounds__(256)
void prep_LT(const float* __restrict__ L, unsigned short* __restrict__ LT)
{
    const long i = (long)blockIdx.x * 256 + threadIdx.x;   // over R_DIM*K_DIM
    const long r = i >> 12; const long k = i & 4095;
    LT[r * K_DIM + k] = f2bf(L[k * R_DIM + r]);
}

// ===========================================================================
// fp32 VALU GEMM — K1 base + fallback path.
// ===========================================================================
template<bool BT>
__global__ __launch_bounds__(256)
void gemm128(const float* __restrict__ A, const float* __restrict__ B,
             float* __restrict__ C, int M, int N, int Kc)
{
    __shared__ __align__(16) float Asl[16][132];
    __shared__ __align__(16) float Bsl[16][132];

    const int tid = threadIdx.x;
    const int tx = tid & 15, ty = tid >> 4;
    const long m0 = (long)blockIdx.x * 128;
    const long n0 = (long)blockIdx.y * 128;

    float acc[8][8];
#pragma unroll
    for (int i = 0; i < 8; ++i)
#pragma unroll
        for (int j = 0; j < 8; ++j) acc[i][j] = 0.f;

    for (int k0 = 0; k0 < Kc; k0 += 16) {
#pragma unroll
        for (int q = 0; q < 2; ++q) {
            int fi = tid + 256 * q, row = fi >> 2, col = (fi & 3) * 4;
            float4 v = *(const float4*)(A + (m0 + row) * (long)Kc + k0 + col);
            Asl[col + 0][row] = v.x; Asl[col + 1][row] = v.y;
            Asl[col + 2][row] = v.z; Asl[col + 3][row] = v.w;
        }
        if (BT) {
#pragma unroll
            for (int q = 0; q < 2; ++q) {
                int fi = tid + 256 * q, row = fi >> 2, col = (fi & 3) * 4;
                float4 v = *(const float4*)(B + (n0 + row) * (long)Kc + k0 + col);
                Bsl[col + 0][row] = v.x; Bsl[col + 1][row] = v.y;
                Bsl[col + 2][row] = v.z; Bsl[col + 3][row] = v.w;
            }
        } else {
#pragma unroll
            for (int q = 0; q < 2; ++q) {
                int fi = tid + 256 * q, row = fi >> 5, col = (fi & 31) * 4;
                float4 v = *(const float4*)(B + (k0 + row) * (long)N + n0 + col);
                *(float4*)&Bsl[row][col] = v;
            }
        }
        __syncthreads();
#pragma unroll
        for (int kk = 0; kk < 16; ++kk) {
            float a[8], b[8];
            *(float4*)&a[0] = *(const float4*)&Asl[kk][ty * 8];
            *(float4*)&a[4] = *(const float4*)&Asl[kk][ty * 8 + 4];
            *(float4*)&b[0] = *(const float4*)&Bsl[kk][tx * 8];
            *(float4*)&b[4] = *(const float4*)&Bsl[kk][tx * 8 + 4];
#pragma unroll
            for (int i = 0; i < 8; ++i)
#pragma unroll
                for (int j = 0; j < 8; ++j)
                    acc[i][j] = fmaf(a[i], b[j], acc[i][j]);
        }
        __syncthreads();
    }
#pragma unroll
    for (int i = 0; i < 8; ++i) {
        float* p = C + (m0 + ty * 8 + i) * (long)N + n0 + tx * 8;
        *(float4*)p       = make_float4(acc[i][0], acc[i][1], acc[i][2], acc[i][3]);
        *(float4*)(p + 4) = make_float4(acc[i][4], acc[i][5], acc[i][6], acc[i][7]);
    }
}

// ===========================================================================
// K1 with fused split-write: P = A@B (fp32 VALU), epilogue writes
// Ap = [P_hi | P_hi | P_lo] directly (no P materialization).
// ===========================================================================
__global__ __launch_bounds__(256)
void gemm128_hl(const float* __restrict__ A, const float* __restrict__ B,
                unsigned short* __restrict__ Ap, int M, int N, int Kc)
{
    __shared__ __align__(16) float Asl[16][132];
    __shared__ __align__(16) float Bsl[16][132];

    const int tid = threadIdx.x;
    const int tx = tid & 15, ty = tid >> 4;
    const long m0 = (long)blockIdx.x * 128;
    const long n0 = (long)blockIdx.y * 128;

    float acc[8][8];
#pragma unroll
    for (int i = 0; i < 8; ++i)
#pragma unroll
        for (int j = 0; j < 8; ++j) acc[i][j] = 0.f;

    for (int k0 = 0; k0 < Kc; k0 += 16) {
#pragma unroll
        for (int q = 0; q < 2; ++q) {
            int fi = tid + 256 * q, row = fi >> 2, col = (fi & 3) * 4;
            float4 v = *(const float4*)(A + (m0 + row) * (long)Kc + k0 + col);
            Asl[col + 0][row] = v.x; Asl[col + 1][row] = v.y;
            Asl[col + 2][row] = v.z; Asl[col + 3][row] = v.w;
        }
#pragma unroll
        for (int q = 0; q < 2; ++q) {
            int fi = tid + 256 * q, row = fi >> 5, col = (fi & 31) * 4;
            float4 v = *(const float4*)(B + (k0 + row) * (long)N + n0 + col);
            *(float4*)&Bsl[row][col] = v;
        }
        __syncthreads();
#pragma unroll
        for (int kk = 0; kk < 16; ++kk) {
            float a[8], b[8];
            *(float4*)&a[0] = *(const float4*)&Asl[kk][ty * 8];
            *(float4*)&a[4] = *(const float4*)&Asl[kk][ty * 8 + 4];
            *(float4*)&b[0] = *(const float4*)&Bsl[kk][tx * 8];
            *(float4*)&b[4] = *(const float4*)&Bsl[kk][tx * 8 + 4];
#pragma unroll
            for (int i = 0; i < 8; ++i)
#pragma unroll
                for (int j = 0; j < 8; ++j)
                    acc[i][j] = fmaf(a[i], b[j], acc[i][j]);
        }
        __syncthreads();
    }
#pragma unroll
    for (int i = 0; i < 8; ++i) {
        const long row = m0 + ty * 8 + i;
        const int  cb  = (int)n0 + tx * 8;
        u16x8 vh, vl;
#pragma unroll
        for (int j = 0; j < 8; ++j) {
            const float x = acc[i][j];
            const unsigned short hi = f2bf(x);
            vh[j] = hi;
            vl[j] = f2bf(x - bf2f(hi));
        }
        unsigned short* rp = Ap + row * KP;
        *(u16x8*)(rp + cb)             = vh;
        *(u16x8*)(rp + R_DIM + cb)     = vh;
        *(u16x8*)(rp + 2 * R_DIM + cb) = vl;
    }
}

// ---------------------------------------------------------------------------
// In-place row softmax (fallback path only)
// ---------------------------------------------------------------------------
__global__ __launch_bounds__(256)
void softmax_rows(float* __restrict__ Mio)
{
    const long n  = blockIdx.x;
    float* row    = Mio + n * (long)K_DIM;
    const int tid = threadIdx.x;

    float4 v[4];
    float lmax = -3.4e38f;
#pragma unroll
    for (int q = 0; q < 4; ++q) {
        v[q] = ((const float4*)row)[tid + 256 * q];
        lmax = fmaxf(lmax, fmaxf(fmaxf(v[q].x, v[q].y), fmaxf(v[q].z, v[q].w)));
    }
    __shared__ float redmax[4], redsum[4];
#pragma unroll
    for (int off = 32; off > 0; off >>= 1)
        lmax = fmaxf(lmax, __shfl_xor(lmax, off));
    if ((tid & 63) == 0) redmax[tid >> 6] = lmax;
    __syncthreads();
    const float gmax = fmaxf(fmaxf(redmax[0], redmax[1]), fmaxf(redmax[2], redmax[3]));

    float lsum = 0.f;
#pragma unroll
    for (int q = 0; q < 4; ++q) {
        v[q].x = __expf(v[q].x - gmax); v[q].y = __expf(v[q].y - gmax);
        v[q].z = __expf(v[q].z - gmax); v[q].w = __expf(v[q].w - gmax);
        lsum += v[q].x + v[q].y + v[q].z + v[q].w;
    }
#pragma unroll
    for (int off = 32; off > 0; off >>= 1)
        lsum += __shfl_xor(lsum, off);
    if ((tid & 63) == 0) redsum[tid >> 6] = lsum;
    __syncthreads();
    const float inv = 1.f / (redsum[0] + redsum[1] + redsum[2] + redsum[3]);
#pragma unroll
    for (int q = 0; q < 4; ++q) {
        v[q].x *= inv; v[q].y *= inv; v[q].z *= inv; v[q].w *= inv;
        ((float4*)row)[tid + 256 * q] = v[q];
    }
}

// ===========================================================================
extern "C" void kernel_launch(void* const* d_in, const int* in_sizes, int n_in,
                              void* d_out, int out_size, void* d_ws, size_t ws_size,
                              hipStream_t stream)
{
    const float* H  = (const float*)d_in[0];
    const float* L  = (const float*)d_in[1];
    const float* Wi = (const float*)d_in[2];

    float* Cout = (float*)d_out;                           // N x R
    float* Aout = (float*)d_out + (size_t)N_ROWS * R_DIM;  // N x K

    const size_t szAp = (size_t)N_ROWS * KP * 2;    // 48 MiB
    const size_t szBp = (size_t)K_DIM * KP * 2;     //  6 MiB
    const size_t szLT = (size_t)R_DIM * K_DIM * 2;  //  2 MiB
    const size_t szPm = (size_t)N_ROWS * KB * 4;    //  4 MiB
    const size_t szPs = (size_t)N_ROWS * KB * 4;    //  4 MiB
    const size_t szSM = (size_t)N_ROWS * 4;         // 128 KiB

    if (ws_size >= szAp + szBp + szLT + szPm + szPs + 2 * szSM) {
        char* w = (char*)d_ws;
        unsigned short* Ap = (unsigned short*)w;                 w += szAp;
        unsigned short* Bp = (unsigned short*)w;                 w += szBp;
        unsigned short* LT = (unsigned short*)w;                 w += szLT;
        float* Pm  = (float*)w;                                  w += szPm;
        float* Ps  = (float*)w;                                  w += szPs;
        float* SMm = (float*)w;                                  w += szSM;
        float* SMi = (float*)w;

        // K1: P = H@W_I (fp32 VALU), split [hi|hi|lo] written directly to Ap
        gemm128_hl<<<dim3(N_ROWS / 128, R_DIM / 128), 256, 0, stream>>>(
            H, Wi, Ap, N_ROWS, R_DIM, R_DIM);
        // Prep split B operand + transposed bf16 L
        prep_B<<<dim3((K_DIM * R_DIM) / 256), 256, 0, stream>>>(L, Bp);
        prep_LT<<<dim3((R_DIM * K_DIM) / 256), 256, 0, stream>>>(L, LT);
        // K2: logits M = A'·B'^T (3-term split bf16 MFMA) + softmax partials
        // grid: x = col-panels (B'-reuse in XCD L2), y = row-panels
        gemm_mfma_nt<<<dim3(K_DIM / 128, N_ROWS / 128), 256, 0, stream>>>(
            Ap, Bp, Aout, Pm, Ps, N_ROWS, K_DIM, KP);
        // combine partials -> per-row (max, 1/sum)
        finalize_ms<<<dim3(N_ROWS / 256), 256, 0, stream>>>(Pm, Ps, SMm, SMi);
        // single-pass: A = softmax applied in place; C = A@L
        softmax_av2<<<dim3(N_ROWS / 64), 512, 0, stream>>>(
            Aout, LT, SMm, SMi, Cout);
    } else {
        // Fallback: round-1 fp32 path
        gemm128<false><<<dim3(N_ROWS / 128, R_DIM / 128), 256, 0, stream>>>(
            H, Wi, Cout, N_ROWS, R_DIM, R_DIM);
        gemm128<true><<<dim3(N_ROWS / 128, K_DIM / 128), 256, 0, stream>>>(
            Cout, L, Aout, N_ROWS, K_DIM, R_DIM);
        softmax_rows<<<dim3(N_ROWS), 256, 0, stream>>>(Aout);
        gemm128<false><<<dim3(N_ROWS / 128, R_DIM / 128), 256, 0, stream>>>(
            Aout, L, Cout, N_ROWS, R_DIM, K_DIM);
    }
}

// Round 4
// 1413.746 us; speedup vs baseline: 1.0247x; 1.0247x over previous
//
#include <hip/hip_runtime.h>
#include <hip/hip_bf16.h>
#include <math.h>
#include <stdint.h>

// Problem constants
constexpr int N_ROWS = 32768;
constexpr int K_DIM  = 4096;
constexpr int R_DIM  = 256;
constexpr int KP     = 3 * R_DIM;   // 768: split-K' for [hi|hi|lo] x [hi|lo|hi]
constexpr int KB     = K_DIM / 128; // 32 col-blocks in K2 grid

typedef __bf16 bf16x8 __attribute__((ext_vector_type(8)));
typedef float  f32x4  __attribute__((ext_vector_type(4)));
typedef unsigned short u16x8 __attribute__((ext_vector_type(8)));

// ---- bf16 helpers (round-to-nearest-even; inputs are finite normals) ----
__device__ __forceinline__ unsigned short f2bf(float x) {
    unsigned u = __float_as_uint(x);
    u += 0x7fffu + ((u >> 16) & 1u);
    return (unsigned short)(u >> 16);
}
__device__ __forceinline__ float bf2f(unsigned short h) {
    return __uint_as_float((unsigned)h << 16);
}

// ---- async global->LDS, 16B per lane, LDS dest = wave-uniform base + lane*16
__device__ __forceinline__ void gl2lds16(const void* gptr, void* lptr) {
    __builtin_amdgcn_global_load_lds(
        (const __attribute__((address_space(1))) unsigned int*)gptr,
        (__attribute__((address_space(3))) unsigned int*)lptr,
        16, 0, 0);
}

// ===========================================================================
// K2: M[m,n] = sum_k A[m,k]*B[n,k], bf16 k-major, C fp32. 128x128 tile, BK=64,
// 256 threads = 4 waves (2x2 of 64x64), 16x16x32 MFMA.
// Both operands staged via global_load_lds with XOR-swizzled layout
// (linear LDS dest + inverse-swizzled global source; read applies same XOR).
// Epilogue emits per-row softmax partials over this block's 128 cols.
// ===========================================================================
__global__ __launch_bounds__(256)
void gemm_mfma_nt2(const unsigned short* __restrict__ A,
                   const unsigned short* __restrict__ B,
                   float* __restrict__ C,
                   float* __restrict__ Pm, float* __restrict__ Ps,
                   int M, int N, int Kc)
{
    __shared__ __align__(16) unsigned short As[128 * 64];  // 16 KiB, swizzled
    __shared__ __align__(16) unsigned short Bs[128 * 64];  // 16 KiB, swizzled
    __shared__ float pm_s[128][2], ps_s[128][2];

    const int tid  = threadIdx.x;
    const int wave = tid >> 6, lane = tid & 63;
    const int wm = wave >> 1, wn = wave & 1;
    const long m0 = (long)blockIdx.x * 128;
    const long n0 = (long)blockIdx.y * 128;

    f32x4 acc[4][4] = {};

    // staging: chunk = 8 rows x 128B (1 KiB); lane -> row lane>>3, slot (lane&7)*16B
    const int lrow  = lane >> 3;                                  // 0..7
    const int loffE = ((((lane & 7) * 16) ^ (lrow << 4)) >> 1);   // swizzled src elem off
    const int kq16 = (lane >> 4) * 16;   // frag 16B slot within 64B half-row
    const int mr = lane & 15;

    for (int k0 = 0; k0 < Kc; k0 += 64) {
#pragma unroll
        for (int c = 0; c < 4; ++c) {
            const int ch = wave * 4 + c;
            gl2lds16(A + (m0 + ch * 8 + lrow) * (long)Kc + k0 + loffE, &As[ch * 512]);
            gl2lds16(B + (n0 + ch * 8 + lrow) * (long)Kc + k0 + loffE, &Bs[ch * 512]);
        }
        __syncthreads();

        bf16x8 af[2][4], bfr[2][4];
#pragma unroll
        for (int ks = 0; ks < 2; ++ks)
#pragma unroll
            for (int t = 0; t < 4; ++t) {
                const int ar = wm * 64 + t * 16 + mr;
                const int br = wn * 64 + t * 16 + mr;
                af[ks][t]  = *(const bf16x8*)((const char*)As +
                             (ar * 128 + ((ks * 64 + kq16) ^ ((ar & 7) << 4))));
                bfr[ks][t] = *(const bf16x8*)((const char*)Bs +
                             (br * 128 + ((ks * 64 + kq16) ^ ((br & 7) << 4))));
            }
#pragma unroll
        for (int ks = 0; ks < 2; ++ks)
#pragma unroll
            for (int i = 0; i < 4; ++i)
#pragma unroll
                for (int j = 0; j < 4; ++j)
                    acc[i][j] = __builtin_amdgcn_mfma_f32_16x16x32_bf16(
                        af[ks][i], bfr[ks][j], acc[i][j], 0, 0, 0);
        __syncthreads();
    }

    // C/D layout: col = lane&15, row = (lane>>4)*4 + reg
    const int col = lane & 15, rquad = (lane >> 4) * 4;
#pragma unroll
    for (int i = 0; i < 4; ++i) {
        const long mrow = m0 + wm * 64 + i * 16 + rquad;
#pragma unroll
        for (int j = 0; j < 4; ++j) {
            float* p = C + mrow * (long)N + n0 + wn * 64 + j * 16 + col;
#pragma unroll
            for (int r = 0; r < 4; ++r) p[(long)r * N] = acc[i][j][r];
        }
    }

    // ---- softmax partials over this block's 128 cols, per row --------------
#pragma unroll
    for (int i = 0; i < 4; ++i) {
#pragma unroll
        for (int r = 0; r < 4; ++r) {
            float mx = fmaxf(fmaxf(acc[i][0][r], acc[i][1][r]),
                             fmaxf(acc[i][2][r], acc[i][3][r]));
#pragma unroll
            for (int off = 1; off < 16; off <<= 1)
                mx = fmaxf(mx, __shfl_xor(mx, off));
            float sm = 0.f;
#pragma unroll
            for (int j = 0; j < 4; ++j) sm += __expf(acc[i][j][r] - mx);
#pragma unroll
            for (int off = 1; off < 16; off <<= 1)
                sm += __shfl_xor(sm, off);
            if (mr == 0) {
                const int rw = wm * 64 + i * 16 + rquad + r;
                pm_s[rw][wn] = mx;
                ps_s[rw][wn] = sm;
            }
        }
    }
    __syncthreads();
    if (tid < 128) {
        const float ma = pm_s[tid][0], mb = pm_s[tid][1];
        const float mx = fmaxf(ma, mb);
        const float s  = ps_s[tid][0] * __expf(ma - mx) +
                         ps_s[tid][1] * __expf(mb - mx);
        Pm[(m0 + tid) * KB + blockIdx.y] = mx;
        Ps[(m0 + tid) * KB + blockIdx.y] = s;
    }
}

// ===========================================================================
// Combine per-block softmax partials -> per-row (max, 1/sum).
// ===========================================================================
__global__ __launch_bounds__(256)
void finalize_ms(const float* __restrict__ Pm, const float* __restrict__ Ps,
                 float* __restrict__ SMm, float* __restrict__ SMi)
{
    const long row = (long)blockIdx.x * 256 + threadIdx.x;
    const float4* pm = (const float4*)(Pm + row * KB);
    const float4* ps = (const float4*)(Ps + row * KB);
    float4 v[8];
    float mx = -3.4e38f;
#pragma unroll
    for (int q = 0; q < 8; ++q) {
        v[q] = pm[q];
        mx = fmaxf(mx, fmaxf(fmaxf(v[q].x, v[q].y), fmaxf(v[q].z, v[q].w)));
    }
    float s = 0.f;
#pragma unroll
    for (int q = 0; q < 8; ++q) {
        float4 w = ps[q];
        s += w.x * __expf(v[q].x - mx) + w.y * __expf(v[q].y - mx) +
             w.z * __expf(v[q].z - mx) + w.w * __expf(v[q].w - mx);
    }
    SMm[row] = mx;
    SMi[row] = 1.f / s;
}

// ===========================================================================
// Pure streaming softmax-apply: A[n,k] = exp(M[n,k]-m_n)*inv_n, in place.
// 4096 blocks x 256 thr; block handles 8 rows; float4 in/out, no LDS/barriers.
// ===========================================================================
__global__ __launch_bounds__(256)
void exp_apply(float* __restrict__ Mio,
               const float* __restrict__ SMm, const float* __restrict__ SMi)
{
    const int tid = threadIdx.x;
    const long r0 = (long)blockIdx.x * 8;
#pragma unroll
    for (int r = 0; r < 8; ++r) {
        const long row = r0 + r;
        const float m = SMm[row], inv = SMi[row];
        float4* p = (float4*)(Mio + row * (long)K_DIM);
#pragma unroll
        for (int it = 0; it < 4; ++it) {
            float4 v = p[it * 256 + tid];
            v.x = __expf(v.x - m) * inv;
            v.y = __expf(v.y - m) * inv;
            v.z = __expf(v.z - m) * inv;
            v.w = __expf(v.w - m) * inv;
            p[it * 256 + tid] = v;
        }
    }
}

// ===========================================================================
// C = A @ LT^T: A (N_ROWS x K_DIM fp32, softmaxed), LT (R_DIM x K_DIM bf16
// k-major). Tile 128 x 256 (full N in one block-col -> A read exactly once).
// 512 thr = 8 waves (2x4 of 64x64), BK=32. A converted fp32->bf16 in staging.
// ===========================================================================
__global__ __launch_bounds__(512)
void gemm_a32_w(const float* __restrict__ A,
                const unsigned short* __restrict__ LT,
                float* __restrict__ C)
{
    __shared__ __align__(16) unsigned short As[128 * 32];  //  8 KiB
    __shared__ __align__(16) unsigned short Bs[256 * 32];  // 16 KiB

    const int tid  = threadIdx.x;
    const int wave = tid >> 6, lane = tid & 63;
    const int wm = wave >> 2, wn = wave & 3;   // 2 x 4 waves of 64x64
    const long m0 = (long)blockIdx.x * 128;

    f32x4 acc[4][4] = {};

    const int kq = (lane >> 4) * 8;
    const int mr = lane & 15;
    // A staging: 512 thr x 8 floats: row tid>>2, cols (tid&3)*8..+7
    const int arow = tid >> 2, acol = (tid & 3) * 8;
    // B staging: 16 chunks of 16 rows x 32 elems (1 KiB); 2 chunks per wave
    const int srow = lane >> 2, skoff = (lane & 3) * 8;

    for (int k0 = 0; k0 < K_DIM; k0 += 32) {
#pragma unroll
        for (int c = 0; c < 2; ++c) {
            const int ch = wave * 2 + c;
            gl2lds16(LT + (ch * 16 + srow) * (long)K_DIM + k0 + skoff, &Bs[ch * 512]);
        }
        {
            const float* g = A + (m0 + arow) * (long)K_DIM + k0 + acol;
            float4 v0 = *(const float4*)(g + 0);
            float4 v1 = *(const float4*)(g + 4);
            u16x8 u;
            u[0] = f2bf(v0.x); u[1] = f2bf(v0.y); u[2] = f2bf(v0.z); u[3] = f2bf(v0.w);
            u[4] = f2bf(v1.x); u[5] = f2bf(v1.y); u[6] = f2bf(v1.z); u[7] = f2bf(v1.w);
            *(u16x8*)&As[arow * 32 + acol] = u;
        }
        __syncthreads();

        bf16x8 af[4], bfr[4];
#pragma unroll
        for (int t = 0; t < 4; ++t) {
            af[t]  = *(const bf16x8*)&As[(wm * 64 + t * 16 + mr) * 32 + kq];
            bfr[t] = *(const bf16x8*)&Bs[(wn * 64 + t * 16 + mr) * 32 + kq];
        }
#pragma unroll
        for (int i = 0; i < 4; ++i)
#pragma unroll
            for (int j = 0; j < 4; ++j)
                acc[i][j] = __builtin_amdgcn_mfma_f32_16x16x32_bf16(
                    af[i], bfr[j], acc[i][j], 0, 0, 0);
        __syncthreads();
    }

    const int col = lane & 15, rquad = (lane >> 4) * 4;
#pragma unroll
    for (int i = 0; i < 4; ++i) {
        const long mrow = m0 + wm * 64 + i * 16 + rquad;
#pragma unroll
        for (int j = 0; j < 4; ++j) {
            float* p = C + mrow * (long)R_DIM + wn * 64 + j * 16 + col;
#pragma unroll
            for (int r = 0; r < 4; ++r) p[(long)r * R_DIM] = acc[i][j][r];
        }
    }
}

// ===========================================================================
// Prep kernels
// ===========================================================================
// B' = [L_hi | L_lo | L_hi]  (K_DIM x 768)
__global__ __launch_bounds__(256)
void prep_B(const float* __restrict__ L, unsigned short* __restrict__ Bp)
{
    const long i = (long)blockIdx.x * 256 + threadIdx.x;   // over K_DIM*R_DIM
    const long k = i >> 8; const int r = (int)(i & 255);
    const float x = L[i];
    const unsigned short hi = f2bf(x);
    const unsigned short lo = f2bf(x - bf2f(hi));
    unsigned short* row = Bp + k * KP;
    row[r] = hi; row[R_DIM + r] = lo; row[2 * R_DIM + r] = hi;
}

// LT[r][k] = bf16(L[k][r])  (256 x 4096) — coalesced writes
__global__ __launch_bounds__(256)
void prep_LT(const float* __restrict__ L, unsigned short* __restrict__ LT)
{
    const long i = (long)blockIdx.x * 256 + threadIdx.x;   // over R_DIM*K_DIM
    const long r = i >> 12; const long k = i & 4095;
    LT[r * K_DIM + k] = f2bf(L[k * R_DIM + r]);
}

// ===========================================================================
// fp32 VALU GEMM — K1 base + fallback path.
// ===========================================================================
template<bool BT>
__global__ __launch_bounds__(256)
void gemm128(const float* __restrict__ A, const float* __restrict__ B,
             float* __restrict__ C, int M, int N, int Kc)
{
    __shared__ __align__(16) float Asl[16][132];
    __shared__ __align__(16) float Bsl[16][132];

    const int tid = threadIdx.x;
    const int tx = tid & 15, ty = tid >> 4;
    const long m0 = (long)blockIdx.x * 128;
    const long n0 = (long)blockIdx.y * 128;

    float acc[8][8];
#pragma unroll
    for (int i = 0; i < 8; ++i)
#pragma unroll
        for (int j = 0; j < 8; ++j) acc[i][j] = 0.f;

    for (int k0 = 0; k0 < Kc; k0 += 16) {
#pragma unroll
        for (int q = 0; q < 2; ++q) {
            int fi = tid + 256 * q, row = fi >> 2, col = (fi & 3) * 4;
            float4 v = *(const float4*)(A + (m0 + row) * (long)Kc + k0 + col);
            Asl[col + 0][row] = v.x; Asl[col + 1][row] = v.y;
            Asl[col + 2][row] = v.z; Asl[col + 3][row] = v.w;
        }
        if (BT) {
#pragma unroll
            for (int q = 0; q < 2; ++q) {
                int fi = tid + 256 * q, row = fi >> 2, col = (fi & 3) * 4;
                float4 v = *(const float4*)(B + (n0 + row) * (long)Kc + k0 + col);
                Bsl[col + 0][row] = v.x; Bsl[col + 1][row] = v.y;
                Bsl[col + 2][row] = v.z; Bsl[col + 3][row] = v.w;
            }
        } else {
#pragma unroll
            for (int q = 0; q < 2; ++q) {
                int fi = tid + 256 * q, row = fi >> 5, col = (fi & 31) * 4;
                float4 v = *(const float4*)(B + (k0 + row) * (long)N + n0 + col);
                *(float4*)&Bsl[row][col] = v;
            }
        }
        __syncthreads();
#pragma unroll
        for (int kk = 0; kk < 16; ++kk) {
            float a[8], b[8];
            *(float4*)&a[0] = *(const float4*)&Asl[kk][ty * 8];
            *(float4*)&a[4] = *(const float4*)&Asl[kk][ty * 8 + 4];
            *(float4*)&b[0] = *(const float4*)&Bsl[kk][tx * 8];
            *(float4*)&b[4] = *(const float4*)&Bsl[kk][tx * 8 + 4];
#pragma unroll
            for (int i = 0; i < 8; ++i)
#pragma unroll
                for (int j = 0; j < 8; ++j)
                    acc[i][j] = fmaf(a[i], b[j], acc[i][j]);
        }
        __syncthreads();
    }
#pragma unroll
    for (int i = 0; i < 8; ++i) {
        float* p = C + (m0 + ty * 8 + i) * (long)N + n0 + tx * 8;
        *(float4*)p       = make_float4(acc[i][0], acc[i][1], acc[i][2], acc[i][3]);
        *(float4*)(p + 4) = make_float4(acc[i][4], acc[i][5], acc[i][6], acc[i][7]);
    }
}

// ===========================================================================
// K1 with fused split-write: P = A@B (fp32 VALU), epilogue writes
// Ap = [P_hi | P_hi | P_lo] directly (no P materialization).
// ===========================================================================
__global__ __launch_bounds__(256)
void gemm128_hl(const float* __restrict__ A, const float* __restrict__ B,
                unsigned short* __restrict__ Ap, int M, int N, int Kc)
{
    __shared__ __align__(16) float Asl[16][132];
    __shared__ __align__(16) float Bsl[16][132];

    const int tid = threadIdx.x;
    const int tx = tid & 15, ty = tid >> 4;
    const long m0 = (long)blockIdx.x * 128;
    const long n0 = (long)blockIdx.y * 128;

    float acc[8][8];
#pragma unroll
    for (int i = 0; i < 8; ++i)
#pragma unroll
        for (int j = 0; j < 8; ++j) acc[i][j] = 0.f;

    for (int k0 = 0; k0 < Kc; k0 += 16) {
#pragma unroll
        for (int q = 0; q < 2; ++q) {
            int fi = tid + 256 * q, row = fi >> 2, col = (fi & 3) * 4;
            float4 v = *(const float4*)(A + (m0 + row) * (long)Kc + k0 + col);
            Asl[col + 0][row] = v.x; Asl[col + 1][row] = v.y;
            Asl[col + 2][row] = v.z; Asl[col + 3][row] = v.w;
        }
#pragma unroll
        for (int q = 0; q < 2; ++q) {
            int fi = tid + 256 * q, row = fi >> 5, col = (fi & 31) * 4;
            float4 v = *(const float4*)(B + (k0 + row) * (long)N + n0 + col);
            *(float4*)&Bsl[row][col] = v;
        }
        __syncthreads();
#pragma unroll
        for (int kk = 0; kk < 16; ++kk) {
            float a[8], b[8];
            *(float4*)&a[0] = *(const float4*)&Asl[kk][ty * 8];
            *(float4*)&a[4] = *(const float4*)&Asl[kk][ty * 8 + 4];
            *(float4*)&b[0] = *(const float4*)&Bsl[kk][tx * 8];
            *(float4*)&b[4] = *(const float4*)&Bsl[kk][tx * 8 + 4];
#pragma unroll
            for (int i = 0; i < 8; ++i)
#pragma unroll
                for (int j = 0; j < 8; ++j)
                    acc[i][j] = fmaf(a[i], b[j], acc[i][j]);
        }
        __syncthreads();
    }
#pragma unroll
    for (int i = 0; i < 8; ++i) {
        const long row = m0 + ty * 8 + i;
        const int  cb  = (int)n0 + tx * 8;
        u16x8 vh, vl;
#pragma unroll
        for (int j = 0; j < 8; ++j) {
            const float x = acc[i][j];
            const unsigned short hi = f2bf(x);
            vh[j] = hi;
            vl[j] = f2bf(x - bf2f(hi));
        }
        unsigned short* rp = Ap + row * KP;
        *(u16x8*)(rp + cb)             = vh;
        *(u16x8*)(rp + R_DIM + cb)     = vh;
        *(u16x8*)(rp + 2 * R_DIM + cb) = vl;
    }
}

// ---------------------------------------------------------------------------
// In-place row softmax (fallback path only)
// ---------------------------------------------------------------------------
__global__ __launch_bounds__(256)
void softmax_rows(float* __restrict__ Mio)
{
    const long n  = blockIdx.x;
    float* row    = Mio + n * (long)K_DIM;
    const int tid = threadIdx.x;

    float4 v[4];
    float lmax = -3.4e38f;
#pragma unroll
    for (int q = 0; q < 4; ++q) {
        v[q] = ((const float4*)row)[tid + 256 * q];
        lmax = fmaxf(lmax, fmaxf(fmaxf(v[q].x, v[q].y), fmaxf(v[q].z, v[q].w)));
    }
    __shared__ float redmax[4], redsum[4];
#pragma unroll
    for (int off = 32; off > 0; off >>= 1)
        lmax = fmaxf(lmax, __shfl_xor(lmax, off));
    if ((tid & 63) == 0) redmax[tid >> 6] = lmax;
    __syncthreads();
    const float gmax = fmaxf(fmaxf(redmax[0], redmax[1]), fmaxf(redmax[2], redmax[3]));

    float lsum = 0.f;
#pragma unroll
    for (int q = 0; q < 4; ++q) {
        v[q].x = __expf(v[q].x - gmax); v[q].y = __expf(v[q].y - gmax);
        v[q].z = __expf(v[q].z - gmax); v[q].w = __expf(v[q].w - gmax);
        lsum += v[q].x + v[q].y + v[q].z + v[q].w;
    }
#pragma unroll
    for (int off = 32; off > 0; off >>= 1)
        lsum += __shfl_xor(lsum, off);
    if ((tid & 63) == 0) redsum[tid >> 6] = lsum;
    __syncthreads();
    const float inv = 1.f / (redsum[0] + redsum[1] + redsum[2] + redsum[3]);
#pragma unroll
    for (int q = 0; q < 4; ++q) {
        v[q].x *= inv; v[q].y *= inv; v[q].z *= inv; v[q].w *= inv;
        ((float4*)row)[tid + 256 * q] = v[q];
    }
}

// ===========================================================================
extern "C" void kernel_launch(void* const* d_in, const int* in_sizes, int n_in,
                              void* d_out, int out_size, void* d_ws, size_t ws_size,
                              hipStream_t stream)
{
    const float* H  = (const float*)d_in[0];
    const float* L  = (const float*)d_in[1];
    const float* Wi = (const float*)d_in[2];

    float* Cout = (float*)d_out;                           // N x R
    float* Aout = (float*)d_out + (size_t)N_ROWS * R_DIM;  // N x K

    const size_t szAp = (size_t)N_ROWS * KP * 2;    // 48 MiB
    const size_t szBp = (size_t)K_DIM * KP * 2;     //  6 MiB
    const size_t szLT = (size_t)R_DIM * K_DIM * 2;  //  2 MiB
    const size_t szPm = (size_t)N_ROWS * KB * 4;    //  4 MiB
    const size_t szPs = (size_t)N_ROWS * KB * 4;    //  4 MiB
    const size_t szSM = (size_t)N_ROWS * 4;         // 128 KiB

    if (ws_size >= szAp + szBp + szLT + szPm + szPs + 2 * szSM) {
        char* w = (char*)d_ws;
        unsigned short* Ap = (unsigned short*)w;                 w += szAp;
        unsigned short* Bp = (unsigned short*)w;                 w += szBp;
        unsigned short* LT = (unsigned short*)w;                 w += szLT;
        float* Pm  = (float*)w;                                  w += szPm;
        float* Ps  = (float*)w;                                  w += szPs;
        float* SMm = (float*)w;                                  w += szSM;
        float* SMi = (float*)w;

        // K1: P = H@W_I (fp32 VALU), split [hi|hi|lo] written directly to Ap
        gemm128_hl<<<dim3(N_ROWS / 128, R_DIM / 128), 256, 0, stream>>>(
            H, Wi, Ap, N_ROWS, R_DIM, R_DIM);
        // Prep split B operand + transposed bf16 L
        prep_B<<<dim3((K_DIM * R_DIM) / 256), 256, 0, stream>>>(L, Bp);
        prep_LT<<<dim3((R_DIM * K_DIM) / 256), 256, 0, stream>>>(L, LT);
        // K2: logits M = A'·B'^T (3-term split bf16 MFMA, BK=64 swizzled)
        //     + per-row softmax partials
        gemm_mfma_nt2<<<dim3(N_ROWS / 128, K_DIM / 128), 256, 0, stream>>>(
            Ap, Bp, Aout, Pm, Ps, N_ROWS, K_DIM, KP);
        // combine partials -> per-row (max, 1/sum)
        finalize_ms<<<dim3(N_ROWS / 256), 256, 0, stream>>>(Pm, Ps, SMm, SMi);
        // pure streaming softmax-apply (in place over M)
        exp_apply<<<dim3(N_ROWS / 8), 256, 0, stream>>>(Aout, SMm, SMi);
        // C = A @ L (tile 128x256: A read exactly once, converted in staging)
        gemm_a32_w<<<dim3(N_ROWS / 128), 512, 0, stream>>>(Aout, LT, Cout);
    } else {
        // Fallback: round-1 fp32 path
        gemm128<false><<<dim3(N_ROWS / 128, R_DIM / 128), 256, 0, stream>>>(
            H, Wi, Cout, N_ROWS, R_DIM, R_DIM);
        gemm128<true><<<dim3(N_ROWS / 128, K_DIM / 128), 256, 0, stream>>>(
            Cout, L, Aout, N_ROWS, K_DIM, R_DIM);
        softmax_rows<<<dim3(N_ROWS), 256, 0, stream>>>(Aout);
        gemm128<false><<<dim3(N_ROWS / 128, R_DIM / 128), 256, 0, stream>>>(
            Aout, L, Cout, N_ROWS, R_DIM, K_DIM);
    }
}

// Round 5
// 1255.569 us; speedup vs baseline: 1.1538x; 1.1260x over previous
//
#include <hip/hip_runtime.h>
#include <hip/hip_bf16.h>
#include <math.h>
#include <stdint.h>

// Problem constants
constexpr int N_ROWS = 32768;
constexpr int K_DIM  = 4096;
constexpr int R_DIM  = 256;
constexpr int KP     = 3 * R_DIM;   // 768: split-K' for [hi|hi|lo] x [hi|lo|hi]
constexpr int KB     = K_DIM / 128; // 32 col-blocks in K2 grid

typedef __bf16 bf16x8 __attribute__((ext_vector_type(8)));
typedef float  f32x4  __attribute__((ext_vector_type(4)));
typedef unsigned short u16x8 __attribute__((ext_vector_type(8)));
typedef unsigned short u16x4 __attribute__((ext_vector_type(4)));

// ---- bf16 helpers (round-to-nearest-even; inputs are finite normals) ----
__device__ __forceinline__ unsigned short f2bf(float x) {
    unsigned u = __float_as_uint(x);
    u += 0x7fffu + ((u >> 16) & 1u);
    return (unsigned short)(u >> 16);
}
__device__ __forceinline__ float bf2f(unsigned short h) {
    return __uint_as_float((unsigned)h << 16);
}

// ---- async global->LDS, 16B per lane, LDS dest = wave-uniform base + lane*16
__device__ __forceinline__ void gl2lds16(const void* gptr, void* lptr) {
    __builtin_amdgcn_global_load_lds(
        (const __attribute__((address_space(1))) unsigned int*)gptr,
        (__attribute__((address_space(3))) unsigned int*)lptr,
        16, 0, 0);
}

// ===========================================================================
// K2: M[m,n] = sum_k A[m,k]*B[n,k], bf16 k-major, C fp32. 128x128 tile, BK=32,
// 256 threads = 4 waves (2x2 of 64x64), 16x16x32 MFMA. (R2-proven: 447 us)
// Epilogue emits per-row softmax partials over this block's 128 cols.
// ===========================================================================
__global__ __launch_bounds__(256)
void gemm_mfma_nt(const unsigned short* __restrict__ A,
                  const unsigned short* __restrict__ B,
                  float* __restrict__ C,
                  float* __restrict__ Pm, float* __restrict__ Ps,
                  int M, int N, int Kc)
{
    __shared__ __align__(16) unsigned short As[128 * 32];
    __shared__ __align__(16) unsigned short Bs[128 * 32];
    __shared__ float pm_s[128][2], ps_s[128][2];

    const int tid  = threadIdx.x;
    const int wave = tid >> 6, lane = tid & 63;
    const int wm = wave >> 1, wn = wave & 1;
    const long m0 = (long)blockIdx.x * 128;
    const long n0 = (long)blockIdx.y * 128;

    f32x4 acc[4][4] = {};

    const int srow  = lane >> 2;        // 0..15 within 16-row chunk
    const int skoff = (lane & 3) * 8;   // bf16 elem offset within 32-wide row
    const int c0 = wave, c1 = wave + 4; // each wave stages 2 chunks per tile
    const int kq = (lane >> 4) * 8;     // frag k-offset 0,8,16,24
    const int mr = lane & 15;

    for (int k0 = 0; k0 < Kc; k0 += 32) {
        gl2lds16(A + (m0 + c0 * 16 + srow) * (long)Kc + k0 + skoff, &As[c0 * 512]);
        gl2lds16(A + (m0 + c1 * 16 + srow) * (long)Kc + k0 + skoff, &As[c1 * 512]);
        gl2lds16(B + (n0 + c0 * 16 + srow) * (long)Kc + k0 + skoff, &Bs[c0 * 512]);
        gl2lds16(B + (n0 + c1 * 16 + srow) * (long)Kc + k0 + skoff, &Bs[c1 * 512]);
        __syncthreads();

        bf16x8 af[4], bfr[4];
#pragma unroll
        for (int t = 0; t < 4; ++t) {
            af[t]  = *(const bf16x8*)&As[(wm * 64 + t * 16 + mr) * 32 + kq];
            bfr[t] = *(const bf16x8*)&Bs[(wn * 64 + t * 16 + mr) * 32 + kq];
        }
#pragma unroll
        for (int i = 0; i < 4; ++i)
#pragma unroll
            for (int j = 0; j < 4; ++j)
                acc[i][j] = __builtin_amdgcn_mfma_f32_16x16x32_bf16(
                    af[i], bfr[j], acc[i][j], 0, 0, 0);
        __syncthreads();
    }

    // C/D layout: col = lane&15, row = (lane>>4)*4 + reg
    const int col = lane & 15, rquad = (lane >> 4) * 4;
#pragma unroll
    for (int i = 0; i < 4; ++i) {
        const long mrow = m0 + wm * 64 + i * 16 + rquad;
#pragma unroll
        for (int j = 0; j < 4; ++j) {
            float* p = C + mrow * (long)N + n0 + wn * 64 + j * 16 + col;
#pragma unroll
            for (int r = 0; r < 4; ++r) p[(long)r * N] = acc[i][j][r];
        }
    }

    // ---- softmax partials over this block's 128 cols, per row --------------
#pragma unroll
    for (int i = 0; i < 4; ++i) {
#pragma unroll
        for (int r = 0; r < 4; ++r) {
            float mx = fmaxf(fmaxf(acc[i][0][r], acc[i][1][r]),
                             fmaxf(acc[i][2][r], acc[i][3][r]));
#pragma unroll
            for (int off = 1; off < 16; off <<= 1)
                mx = fmaxf(mx, __shfl_xor(mx, off));
            float sm = 0.f;
#pragma unroll
            for (int j = 0; j < 4; ++j) sm += __expf(acc[i][j][r] - mx);
#pragma unroll
            for (int off = 1; off < 16; off <<= 1)
                sm += __shfl_xor(sm, off);
            if (mr == 0) {
                const int rw = wm * 64 + i * 16 + rquad + r;
                pm_s[rw][wn] = mx;
                ps_s[rw][wn] = sm;
            }
        }
    }
    __syncthreads();
    if (tid < 128) {
        const float ma = pm_s[tid][0], mb = pm_s[tid][1];
        const float mx = fmaxf(ma, mb);
        const float s  = ps_s[tid][0] * __expf(ma - mx) +
                         ps_s[tid][1] * __expf(mb - mx);
        Pm[(m0 + tid) * KB + blockIdx.y] = mx;
        Ps[(m0 + tid) * KB + blockIdx.y] = s;
    }
}

// ===========================================================================
// Combine per-block softmax partials -> per-row (max, 1/sum).
// ===========================================================================
__global__ __launch_bounds__(256)
void finalize_ms(const float* __restrict__ Pm, const float* __restrict__ Ps,
                 float* __restrict__ SMm, float* __restrict__ SMi)
{
    const long row = (long)blockIdx.x * 256 + threadIdx.x;
    const float4* pm = (const float4*)(Pm + row * KB);
    const float4* ps = (const float4*)(Ps + row * KB);
    float4 v[8];
    float mx = -3.4e38f;
#pragma unroll
    for (int q = 0; q < 8; ++q) {
        v[q] = pm[q];
        mx = fmaxf(mx, fmaxf(fmaxf(v[q].x, v[q].y), fmaxf(v[q].z, v[q].w)));
    }
    float s = 0.f;
#pragma unroll
    for (int q = 0; q < 8; ++q) {
        float4 w = ps[q];
        s += w.x * __expf(v[q].x - mx) + w.y * __expf(v[q].y - mx) +
             w.z * __expf(v[q].z - mx) + w.w * __expf(v[q].w - mx);
    }
    SMm[row] = mx;
    SMi[row] = 1.f / s;
}

// ===========================================================================
// Fused softmax-apply + PV (R1's pass-2, stats precomputed):
//   A[n,k] = exp(M[n,k]-m_n) * inv_n  (in place over M)
//   C[n,r] = (sum_k exp(M-m) * LT[r,k]) * inv_n  (bf16 MFMA)
// Grid: N_ROWS/64 blocks x 512 threads (8 waves = 2 row x 4 col groups).
// Per 64-k tile: stage LT (swizzled src -> linear LDS) + exp/A-write/As-store,
// one barrier, 16 MFMA/wave, barrier. Single-buffered (R1-proven structure).
// ===========================================================================
__global__ __launch_bounds__(512)
void softmax_av_pv(float* __restrict__ Mio,
                   const unsigned short* __restrict__ LT,
                   const float* __restrict__ SMm, const float* __restrict__ SMi,
                   float* __restrict__ C)
{
    __shared__ __align__(16) unsigned short Bs[R_DIM * 64]; // 32 KiB (swizzled)
    __shared__ __align__(16) unsigned short As[64 * 64];    //  8 KiB (swizzled)
    __shared__ float sm_m[64], sm_inv[64];

    const int tid  = threadIdx.x;
    const int wave = tid >> 6, lane = tid & 63;
    const long m0 = (long)blockIdx.x * 64;

    if (tid < 64) { sm_m[tid] = SMm[m0 + tid]; sm_inv[tid] = SMi[m0 + tid]; }
    __syncthreads();

    f32x4 acc[2][4] = {};
    const int wm = wave >> 2, wn = wave & 3;  // wave tile: 32 rows x 64 cols
    const int mr = lane & 15;
    const int kq16 = (lane >> 4) * 16;        // byte offset of frag within 32-k

    for (int k0 = 0; k0 < K_DIM; k0 += 64) {
        // ---- stage LT tile (256 r x 64 k) via async DMA, source pre-swizzled
#pragma unroll
        for (int q = 0; q < 4; ++q) {
            const int rbase = q * 64 + wave * 8;
            const int rloc  = rbase + (lane >> 3);
            const int phys  = (lane & 7) * 16;                 // byte in row
            const int kbyte = phys ^ ((rloc & 7) << 4);        // src byte
            gl2lds16((const char*)LT + (long)rloc * (K_DIM * 2) + (long)k0 * 2 + kbyte,
                     &Bs[rbase * 64]);
        }
        // ---- stage A tile (64 rows x 64 k): exp, global A write, LDS bf16 --
#pragma unroll
        for (int p = 0; p < 2; ++p) {
            const int row = p * 32 + wave * 4 + (lane >> 4);
            const int col = (lane & 15) * 4;
            float* gp = Mio + (m0 + row) * (long)K_DIM + k0 + col;
            float4 v = *(const float4*)gp;
            const float mrow = sm_m[row], inv = sm_inv[row];
            float e0 = __expf(v.x - mrow), e1 = __expf(v.y - mrow);
            float e2 = __expf(v.z - mrow), e3 = __expf(v.w - mrow);
            *(float4*)gp = make_float4(e0 * inv, e1 * inv, e2 * inv, e3 * inv);
            u16x4 u;
            u[0] = f2bf(e0); u[1] = f2bf(e1); u[2] = f2bf(e2); u[3] = f2bf(e3);
            const int byte = (row * 128 + col * 2) ^ ((row & 7) << 4);
            *(u16x4*)((char*)As + byte) = u;
        }
        __syncthreads();

        // ---- MFMA: 2x4 tiles x 2 k-slices ----------------------------------
#pragma unroll
        for (int ks = 0; ks < 2; ++ks) {
            bf16x8 af[2], bfr[4];
#pragma unroll
            for (int t = 0; t < 2; ++t) {
                const int arow = wm * 32 + t * 16 + mr;
                const int ab = (arow * 128 + ks * 64 + kq16) ^ ((arow & 7) << 4);
                af[t] = *(const bf16x8*)((const char*)As + ab);
            }
#pragma unroll
            for (int t = 0; t < 4; ++t) {
                const int brow = wn * 64 + t * 16 + mr;
                const int bb = (brow * 128 + ks * 64 + kq16) ^ ((brow & 7) << 4);
                bfr[t] = *(const bf16x8*)((const char*)Bs + bb);
            }
#pragma unroll
            for (int i = 0; i < 2; ++i)
#pragma unroll
                for (int j = 0; j < 4; ++j)
                    acc[i][j] = __builtin_amdgcn_mfma_f32_16x16x32_bf16(
                        af[i], bfr[j], acc[i][j], 0, 0, 0);
        }
        __syncthreads();
    }

    // ---- epilogue: scale by 1/s, write C -----------------------------------
    const int col = lane & 15, rquad = (lane >> 4) * 4;
#pragma unroll
    for (int i = 0; i < 2; ++i) {
        const int lrow0 = wm * 32 + i * 16 + rquad;
#pragma unroll
        for (int j = 0; j < 4; ++j) {
            float* p = C + (m0 + lrow0) * (long)R_DIM + wn * 64 + j * 16 + col;
#pragma unroll
            for (int r = 0; r < 4; ++r)
                p[(long)r * R_DIM] = acc[i][j][r] * sm_inv[lrow0 + r];
        }
    }
}

// ===========================================================================
// Prep kernels
// ===========================================================================
// B' = [L_hi | L_lo | L_hi]  (K_DIM x 768)
__global__ __launch_bounds__(256)
void prep_B(const float* __restrict__ L, unsigned short* __restrict__ Bp)
{
    const long i = (long)blockIdx.x * 256 + threadIdx.x;   // over K_DIM*R_DIM
    const long k = i >> 8; const int r = (int)(i & 255);
    const float x = L[i];
    const unsigned short hi = f2bf(x);
    const unsigned short lo = f2bf(x - bf2f(hi));
    unsigned short* row = Bp + k * KP;
    row[r] = hi; row[R_DIM + r] = lo; row[2 * R_DIM + r] = hi;
}

// LT[r][k] = bf16(L[k][r])  (256 x 4096) — coalesced writes
__global__ __launch_bounds__(256)
void prep_LT(const float* __restrict__ L, unsigned short* __restrict__ LT)
{
    const long i = (long)blockIdx.x * 256 + threadIdx.x;   // over R_DIM*K_DIM
    const long r = i >> 12; const long k = i & 4095;
    LT[r * K_DIM + k] = f2bf(L[k * R_DIM + r]);
}

// ===========================================================================
// fp32 VALU GEMM — K1 base + fallback path.
// ===========================================================================
template<bool BT>
__global__ __launch_bounds__(256)
void gemm128(const float* __restrict__ A, const float* __restrict__ B,
             float* __restrict__ C, int M, int N, int Kc)
{
    __shared__ __align__(16) float Asl[16][132];
    __shared__ __align__(16) float Bsl[16][132];

    const int tid = threadIdx.x;
    const int tx = tid & 15, ty = tid >> 4;
    const long m0 = (long)blockIdx.x * 128;
    const long n0 = (long)blockIdx.y * 128;

    float acc[8][8];
#pragma unroll
    for (int i = 0; i < 8; ++i)
#pragma unroll
        for (int j = 0; j < 8; ++j) acc[i][j] = 0.f;

    for (int k0 = 0; k0 < Kc; k0 += 16) {
#pragma unroll
        for (int q = 0; q < 2; ++q) {
            int fi = tid + 256 * q, row = fi >> 2, col = (fi & 3) * 4;
            float4 v = *(const float4*)(A + (m0 + row) * (long)Kc + k0 + col);
            Asl[col + 0][row] = v.x; Asl[col + 1][row] = v.y;
            Asl[col + 2][row] = v.z; Asl[col + 3][row] = v.w;
        }
        if (BT) {
#pragma unroll
            for (int q = 0; q < 2; ++q) {
                int fi = tid + 256 * q, row = fi >> 2, col = (fi & 3) * 4;
                float4 v = *(const float4*)(B + (n0 + row) * (long)Kc + k0 + col);
                Bsl[col + 0][row] = v.x; Bsl[col + 1][row] = v.y;
                Bsl[col + 2][row] = v.z; Bsl[col + 3][row] = v.w;
            }
        } else {
#pragma unroll
            for (int q = 0; q < 2; ++q) {
                int fi = tid + 256 * q, row = fi >> 5, col = (fi & 31) * 4;
                float4 v = *(const float4*)(B + (k0 + row) * (long)N + n0 + col);
                *(float4*)&Bsl[row][col] = v;
            }
        }
        __syncthreads();
#pragma unroll
        for (int kk = 0; kk < 16; ++kk) {
            float a[8], b[8];
            *(float4*)&a[0] = *(const float4*)&Asl[kk][ty * 8];
            *(float4*)&a[4] = *(const float4*)&Asl[kk][ty * 8 + 4];
            *(float4*)&b[0] = *(const float4*)&Bsl[kk][tx * 8];
            *(float4*)&b[4] = *(const float4*)&Bsl[kk][tx * 8 + 4];
#pragma unroll
            for (int i = 0; i < 8; ++i)
#pragma unroll
                for (int j = 0; j < 8; ++j)
                    acc[i][j] = fmaf(a[i], b[j], acc[i][j]);
        }
        __syncthreads();
    }
#pragma unroll
    for (int i = 0; i < 8; ++i) {
        float* p = C + (m0 + ty * 8 + i) * (long)N + n0 + tx * 8;
        *(float4*)p       = make_float4(acc[i][0], acc[i][1], acc[i][2], acc[i][3]);
        *(float4*)(p + 4) = make_float4(acc[i][4], acc[i][5], acc[i][6], acc[i][7]);
    }
}

// ===========================================================================
// K1 with fused split-write: P = A@B (fp32 VALU), epilogue writes
// Ap = [P_hi | P_hi | P_lo] directly (no P materialization).
// ===========================================================================
__global__ __launch_bounds__(256)
void gemm128_hl(const float* __restrict__ A, const float* __restrict__ B,
                unsigned short* __restrict__ Ap, int M, int N, int Kc)
{
    __shared__ __align__(16) float Asl[16][132];
    __shared__ __align__(16) float Bsl[16][132];

    const int tid = threadIdx.x;
    const int tx = tid & 15, ty = tid >> 4;
    const long m0 = (long)blockIdx.x * 128;
    const long n0 = (long)blockIdx.y * 128;

    float acc[8][8];
#pragma unroll
    for (int i = 0; i < 8; ++i)
#pragma unroll
        for (int j = 0; j < 8; ++j) acc[i][j] = 0.f;

    for (int k0 = 0; k0 < Kc; k0 += 16) {
#pragma unroll
        for (int q = 0; q < 2; ++q) {
            int fi = tid + 256 * q, row = fi >> 2, col = (fi & 3) * 4;
            float4 v = *(const float4*)(A + (m0 + row) * (long)Kc + k0 + col);
            Asl[col + 0][row] = v.x; Asl[col + 1][row] = v.y;
            Asl[col + 2][row] = v.z; Asl[col + 3][row] = v.w;
        }
#pragma unroll
        for (int q = 0; q < 2; ++q) {
            int fi = tid + 256 * q, row = fi >> 5, col = (fi & 31) * 4;
            float4 v = *(const float4*)(B + (k0 + row) * (long)N + n0 + col);
            *(float4*)&Bsl[row][col] = v;
        }
        __syncthreads();
#pragma unroll
        for (int kk = 0; kk < 16; ++kk) {
            float a[8], b[8];
            *(float4*)&a[0] = *(const float4*)&Asl[kk][ty * 8];
            *(float4*)&a[4] = *(const float4*)&Asl[kk][ty * 8 + 4];
            *(float4*)&b[0] = *(const float4*)&Bsl[kk][tx * 8];
            *(float4*)&b[4] = *(const float4*)&Bsl[kk][tx * 8 + 4];
#pragma unroll
            for (int i = 0; i < 8; ++i)
#pragma unroll
                for (int j = 0; j < 8; ++j)
                    acc[i][j] = fmaf(a[i], b[j], acc[i][j]);
        }
        __syncthreads();
    }
#pragma unroll
    for (int i = 0; i < 8; ++i) {
        const long row = m0 + ty * 8 + i;
        const int  cb  = (int)n0 + tx * 8;
        u16x8 vh, vl;
#pragma unroll
        for (int j = 0; j < 8; ++j) {
            const float x = acc[i][j];
            const unsigned short hi = f2bf(x);
            vh[j] = hi;
            vl[j] = f2bf(x - bf2f(hi));
        }
        unsigned short* rp = Ap + row * KP;
        *(u16x8*)(rp + cb)             = vh;
        *(u16x8*)(rp + R_DIM + cb)     = vh;
        *(u16x8*)(rp + 2 * R_DIM + cb) = vl;
    }
}

// ---------------------------------------------------------------------------
// In-place row softmax (fallback path only)
// ---------------------------------------------------------------------------
__global__ __launch_bounds__(256)
void softmax_rows(float* __restrict__ Mio)
{
    const long n  = blockIdx.x;
    float* row    = Mio + n * (long)K_DIM;
    const int tid = threadIdx.x;

    float4 v[4];
    float lmax = -3.4e38f;
#pragma unroll
    for (int q = 0; q < 4; ++q) {
        v[q] = ((const float4*)row)[tid + 256 * q];
        lmax = fmaxf(lmax, fmaxf(fmaxf(v[q].x, v[q].y), fmaxf(v[q].z, v[q].w)));
    }
    __shared__ float redmax[4], redsum[4];
#pragma unroll
    for (int off = 32; off > 0; off >>= 1)
        lmax = fmaxf(lmax, __shfl_xor(lmax, off));
    if ((tid & 63) == 0) redmax[tid >> 6] = lmax;
    __syncthreads();
    const float gmax = fmaxf(fmaxf(redmax[0], redmax[1]), fmaxf(redmax[2], redmax[3]));

    float lsum = 0.f;
#pragma unroll
    for (int q = 0; q < 4; ++q) {
        v[q].x = __expf(v[q].x - gmax); v[q].y = __expf(v[q].y - gmax);
        v[q].z = __expf(v[q].z - gmax); v[q].w = __expf(v[q].w - gmax);
        lsum += v[q].x + v[q].y + v[q].z + v[q].w;
    }
#pragma unroll
    for (int off = 32; off > 0; off >>= 1)
        lsum += __shfl_xor(lsum, off);
    if ((tid & 63) == 0) redsum[tid >> 6] = lsum;
    __syncthreads();
    const float inv = 1.f / (redsum[0] + redsum[1] + redsum[2] + redsum[3]);
#pragma unroll
    for (int q = 0; q < 4; ++q) {
        v[q].x *= inv; v[q].y *= inv; v[q].z *= inv; v[q].w *= inv;
        ((float4*)row)[tid + 256 * q] = v[q];
    }
}

// ===========================================================================
extern "C" void kernel_launch(void* const* d_in, const int* in_sizes, int n_in,
                              void* d_out, int out_size, void* d_ws, size_t ws_size,
                              hipStream_t stream)
{
    const float* H  = (const float*)d_in[0];
    const float* L  = (const float*)d_in[1];
    const float* Wi = (const float*)d_in[2];

    float* Cout = (float*)d_out;                           // N x R
    float* Aout = (float*)d_out + (size_t)N_ROWS * R_DIM;  // N x K

    const size_t szAp = (size_t)N_ROWS * KP * 2;    // 48 MiB
    const size_t szBp = (size_t)K_DIM * KP * 2;     //  6 MiB
    const size_t szLT = (size_t)R_DIM * K_DIM * 2;  //  2 MiB
    const size_t szPm = (size_t)N_ROWS * KB * 4;    //  4 MiB
    const size_t szPs = (size_t)N_ROWS * KB * 4;    //  4 MiB
    const size_t szSM = (size_t)N_ROWS * 4;         // 128 KiB

    if (ws_size >= szAp + szBp + szLT + szPm + szPs + 2 * szSM) {
        char* w = (char*)d_ws;
        unsigned short* Ap = (unsigned short*)w;                 w += szAp;
        unsigned short* Bp = (unsigned short*)w;                 w += szBp;
        unsigned short* LT = (unsigned short*)w;                 w += szLT;
        float* Pm  = (float*)w;                                  w += szPm;
        float* Ps  = (float*)w;                                  w += szPs;
        float* SMm = (float*)w;                                  w += szSM;
        float* SMi = (float*)w;

        // K1: P = H@W_I (fp32 VALU), split [hi|hi|lo] written directly to Ap
        gemm128_hl<<<dim3(N_ROWS / 128, R_DIM / 128), 256, 0, stream>>>(
            H, Wi, Ap, N_ROWS, R_DIM, R_DIM);
        // Prep split B operand + transposed bf16 L
        prep_B<<<dim3((K_DIM * R_DIM) / 256), 256, 0, stream>>>(L, Bp);
        prep_LT<<<dim3((R_DIM * K_DIM) / 256), 256, 0, stream>>>(L, LT);
        // K2: logits M = A'·B'^T (3-term split bf16 MFMA) + softmax partials
        gemm_mfma_nt<<<dim3(N_ROWS / 128, K_DIM / 128), 256, 0, stream>>>(
            Ap, Bp, Aout, Pm, Ps, N_ROWS, K_DIM, KP);
        // combine partials -> per-row (max, 1/sum)
        finalize_ms<<<dim3(N_ROWS / 256), 256, 0, stream>>>(Pm, Ps, SMm, SMi);
        // fused softmax-apply + PV (R1 pass-2 structure, stats precomputed)
        softmax_av_pv<<<dim3(N_ROWS / 64), 512, 0, stream>>>(
            Aout, LT, SMm, SMi, Cout);
    } else {
        // Fallback: round-1 fp32 path
        gemm128<false><<<dim3(N_ROWS / 128, R_DIM / 128), 256, 0, stream>>>(
            H, Wi, Cout, N_ROWS, R_DIM, R_DIM);
        gemm128<true><<<dim3(N_ROWS / 128, K_DIM / 128), 256, 0, stream>>>(
            Cout, L, Aout, N_ROWS, K_DIM, R_DIM);
        softmax_rows<<<dim3(N_ROWS), 256, 0, stream>>>(Aout);
        gemm128<false><<<dim3(N_ROWS / 128, R_DIM / 128), 256, 0, stream>>>(
            Aout, L, Cout, N_ROWS, R_DIM, K_DIM);
    }
}

// Round 6
// 1204.712 us; speedup vs baseline: 1.2025x; 1.0422x over previous
//
#include <hip/hip_runtime.h>
#include <hip/hip_bf16.h>
#include <math.h>
#include <stdint.h>

// Problem constants
constexpr int N_ROWS = 32768;
constexpr int K_DIM  = 4096;
constexpr int R_DIM  = 256;
constexpr int KP     = 3 * R_DIM;   // 768: split-K' for [hi|hi|lo] x [hi|lo|hi]
constexpr int KB     = K_DIM / 128; // 32 col-blocks in K2 grid

typedef __bf16 bf16x8 __attribute__((ext_vector_type(8)));
typedef float  f32x4  __attribute__((ext_vector_type(4)));
typedef unsigned short u16x8 __attribute__((ext_vector_type(8)));
typedef unsigned short u16x4 __attribute__((ext_vector_type(4)));

// ---- bf16 helpers (round-to-nearest-even; inputs are finite normals) ----
__device__ __forceinline__ unsigned short f2bf(float x) {
    unsigned u = __float_as_uint(x);
    u += 0x7fffu + ((u >> 16) & 1u);
    return (unsigned short)(u >> 16);
}
__device__ __forceinline__ float bf2f(unsigned short h) {
    return __uint_as_float((unsigned)h << 16);
}

// ---- async global->LDS, 16B per lane, LDS dest = wave-uniform base + lane*16
__device__ __forceinline__ void gl2lds16(const void* gptr, void* lptr) {
    __builtin_amdgcn_global_load_lds(
        (const __attribute__((address_space(1))) unsigned int*)gptr,
        (__attribute__((address_space(3))) unsigned int*)lptr,
        16, 0, 0);
}

// ===========================================================================
// K2: M[m,n] = sum_k A[m,k]*B[n,k], bf16 k-major, C fp32. 128x128 tile, BK=32,
// 256 threads = 4 waves (2x2 of 64x64), 16x16x32 MFMA. (R2/R5-proven core.)
// Grid: 1-D, 8192 blocks, decoded as (xg, y, xi): 32x32 super-blocks so the
// A'-panel group (6.3 MB) + B' panel stay L2-resident across the y-sweep ->
// gl2lds A-loads become L2 hits, shrinking the per-iteration vmcnt-drain.
// Epilogue emits per-row softmax partials over this block's 128 cols.
// ===========================================================================
__global__ __launch_bounds__(256)
void gemm_mfma_nt(const unsigned short* __restrict__ A,
                  const unsigned short* __restrict__ B,
                  float* __restrict__ C,
                  float* __restrict__ Pm, float* __restrict__ Ps,
                  int M, int N, int Kc)
{
    __shared__ __align__(16) unsigned short As[128 * 32];
    __shared__ __align__(16) unsigned short Bs[128 * 32];
    __shared__ float pm_s[128][2], ps_s[128][2];

    const int tid  = threadIdx.x;
    const int wave = tid >> 6, lane = tid & 63;
    const int wm = wave >> 1, wn = wave & 1;

    // bijective 1-D decode: bid = xg*1024 + y*32 + xi
    const int bid = blockIdx.x;
    const int xg = bid >> 10;          // row super-group 0..7
    const int yb = (bid >> 5) & 31;    // col-panel     0..31
    const int xi = bid & 31;           // row-panel within group
    const long m0 = (long)(xg * 32 + xi) * 128;
    const long n0 = (long)yb * 128;

    f32x4 acc[4][4] = {};

    const int srow  = lane >> 2;        // 0..15 within 16-row chunk
    const int skoff = (lane & 3) * 8;   // bf16 elem offset within 32-wide row
    const int c0 = wave, c1 = wave + 4; // each wave stages 2 chunks per tile
    const int kq = (lane >> 4) * 8;     // frag k-offset 0,8,16,24
    const int mr = lane & 15;

    for (int k0 = 0; k0 < Kc; k0 += 32) {
        gl2lds16(A + (m0 + c0 * 16 + srow) * (long)Kc + k0 + skoff, &As[c0 * 512]);
        gl2lds16(A + (m0 + c1 * 16 + srow) * (long)Kc + k0 + skoff, &As[c1 * 512]);
        gl2lds16(B + (n0 + c0 * 16 + srow) * (long)Kc + k0 + skoff, &Bs[c0 * 512]);
        gl2lds16(B + (n0 + c1 * 16 + srow) * (long)Kc + k0 + skoff, &Bs[c1 * 512]);
        __syncthreads();

        bf16x8 af[4], bfr[4];
#pragma unroll
        for (int t = 0; t < 4; ++t) {
            af[t]  = *(const bf16x8*)&As[(wm * 64 + t * 16 + mr) * 32 + kq];
            bfr[t] = *(const bf16x8*)&Bs[(wn * 64 + t * 16 + mr) * 32 + kq];
        }
#pragma unroll
        for (int i = 0; i < 4; ++i)
#pragma unroll
            for (int j = 0; j < 4; ++j)
                acc[i][j] = __builtin_amdgcn_mfma_f32_16x16x32_bf16(
                    af[i], bfr[j], acc[i][j], 0, 0, 0);
        __syncthreads();
    }

    // C/D layout: col = lane&15, row = (lane>>4)*4 + reg
    const int col = lane & 15, rquad = (lane >> 4) * 4;
#pragma unroll
    for (int i = 0; i < 4; ++i) {
        const long mrow = m0 + wm * 64 + i * 16 + rquad;
#pragma unroll
        for (int j = 0; j < 4; ++j) {
            float* p = C + mrow * (long)N + n0 + wn * 64 + j * 16 + col;
#pragma unroll
            for (int r = 0; r < 4; ++r) p[(long)r * N] = acc[i][j][r];
        }
    }

    // ---- softmax partials over this block's 128 cols, per row --------------
#pragma unroll
    for (int i = 0; i < 4; ++i) {
#pragma unroll
        for (int r = 0; r < 4; ++r) {
            float mx = fmaxf(fmaxf(acc[i][0][r], acc[i][1][r]),
                             fmaxf(acc[i][2][r], acc[i][3][r]));
#pragma unroll
            for (int off = 1; off < 16; off <<= 1)
                mx = fmaxf(mx, __shfl_xor(mx, off));
            float sm = 0.f;
#pragma unroll
            for (int j = 0; j < 4; ++j) sm += __expf(acc[i][j][r] - mx);
#pragma unroll
            for (int off = 1; off < 16; off <<= 1)
                sm += __shfl_xor(sm, off);
            if (mr == 0) {
                const int rw = wm * 64 + i * 16 + rquad + r;
                pm_s[rw][wn] = mx;
                ps_s[rw][wn] = sm;
            }
        }
    }
    __syncthreads();
    if (tid < 128) {
        const float ma = pm_s[tid][0], mb = pm_s[tid][1];
        const float mx = fmaxf(ma, mb);
        const float s  = ps_s[tid][0] * __expf(ma - mx) +
                         ps_s[tid][1] * __expf(mb - mx);
        Pm[(m0 + tid) * KB + yb] = mx;
        Ps[(m0 + tid) * KB + yb] = s;
    }
}

// ===========================================================================
// Combine per-block softmax partials -> per-row (max, 1/sum).
// ===========================================================================
__global__ __launch_bounds__(256)
void finalize_ms(const float* __restrict__ Pm, const float* __restrict__ Ps,
                 float* __restrict__ SMm, float* __restrict__ SMi)
{
    const long row = (long)blockIdx.x * 256 + threadIdx.x;
    const float4* pm = (const float4*)(Pm + row * KB);
    const float4* ps = (const float4*)(Ps + row * KB);
    float4 v[8];
    float mx = -3.4e38f;
#pragma unroll
    for (int q = 0; q < 8; ++q) {
        v[q] = pm[q];
        mx = fmaxf(mx, fmaxf(fmaxf(v[q].x, v[q].y), fmaxf(v[q].z, v[q].w)));
    }
    float s = 0.f;
#pragma unroll
    for (int q = 0; q < 8; ++q) {
        float4 w = ps[q];
        s += w.x * __expf(v[q].x - mx) + w.y * __expf(v[q].y - mx) +
             w.z * __expf(v[q].z - mx) + w.w * __expf(v[q].w - mx);
    }
    SMm[row] = mx;
    SMi[row] = 1.f / s;
}

// ===========================================================================
// Fused softmax-apply + PV (R5 structure + T14 async-stage split):
//   A[n,k] = exp(M[n,k]-m_n) * inv_n  (in place over M)
//   C[n,r] = (sum_k exp(M-m) * LT[r,k]) * inv_n  (bf16 MFMA)
// Grid: N_ROWS/64 blocks x 512 threads (8 waves = 2 row x 4 col groups).
// Per 64-k tile: stage LT (swizzled src) + exp/A-write/As-store from regs
// PREFETCHED during the previous tile's MFMA (loads issued between barrier1
// and the MFMA cluster, drained at barrier2 -> latency hidden under MFMA).
// ===========================================================================
__global__ __launch_bounds__(512)
void softmax_av_pv(float* __restrict__ Mio,
                   const unsigned short* __restrict__ LT,
                   const float* __restrict__ SMm, const float* __restrict__ SMi,
                   float* __restrict__ C)
{
    __shared__ __align__(16) unsigned short Bs[R_DIM * 64]; // 32 KiB (swizzled)
    __shared__ __align__(16) unsigned short As[64 * 64];    //  8 KiB (swizzled)
    __shared__ float sm_m[64], sm_inv[64];

    const int tid  = threadIdx.x;
    const int wave = tid >> 6, lane = tid & 63;
    const long m0 = (long)blockIdx.x * 64;

    if (tid < 64) { sm_m[tid] = SMm[m0 + tid]; sm_inv[tid] = SMi[m0 + tid]; }
    __syncthreads();

    f32x4 acc[2][4] = {};
    const int wm = wave >> 2, wn = wave & 3;  // wave tile: 32 rows x 64 cols
    const int mr = lane & 15;
    const int kq16 = (lane >> 4) * 16;        // byte offset of frag within 32-k

    // A-emit mapping: each thread owns 2 rows (p=0/1), 4 cols
    const int arow0 = wave * 4 + (lane >> 4);
    const int arow1 = 32 + arow0;
    const int acolE = (lane & 15) * 4;
    float* const gp0 = Mio + (m0 + arow0) * (long)K_DIM + acolE;
    float* const gp1 = Mio + (m0 + arow1) * (long)K_DIM + acolE;
    const int ab0 = (arow0 * 128 + acolE * 2) ^ ((arow0 & 7) << 4);
    const int ab1 = (arow1 * 128 + acolE * 2) ^ ((arow1 & 7) << 4);
    const float mm0 = sm_m[arow0], ii0 = sm_inv[arow0];
    const float mm1 = sm_m[arow1], ii1 = sm_inv[arow1];

    // prologue: prefetch tile 0's M values
    float4 va0 = *(const float4*)gp0;
    float4 va1 = *(const float4*)gp1;

    for (int t = 0; t < K_DIM / 64; ++t) {
        const int k0 = t * 64;
        // ---- stage LT tile (256 r x 64 k) via async DMA, source pre-swizzled
#pragma unroll
        for (int q = 0; q < 4; ++q) {
            const int rbase = q * 64 + wave * 8;
            const int rloc  = rbase + (lane >> 3);
            const int phys  = (lane & 7) * 16;                 // byte in row
            const int kbyte = phys ^ ((rloc & 7) << 4);        // src byte
            gl2lds16((const char*)LT + (long)rloc * (K_DIM * 2) + (long)k0 * 2 + kbyte,
                     &Bs[rbase * 64]);
        }
        // ---- emit A tile t from prefetched regs: exp, global write, LDS ----
        {
            float e0 = __expf(va0.x - mm0), e1 = __expf(va0.y - mm0);
            float e2 = __expf(va0.z - mm0), e3 = __expf(va0.w - mm0);
            *(float4*)(gp0 + k0) = make_float4(e0 * ii0, e1 * ii0, e2 * ii0, e3 * ii0);
            u16x4 u0; u0[0] = f2bf(e0); u0[1] = f2bf(e1); u0[2] = f2bf(e2); u0[3] = f2bf(e3);
            *(u16x4*)((char*)As + ab0) = u0;

            float f0 = __expf(va1.x - mm1), f1 = __expf(va1.y - mm1);
            float f2 = __expf(va1.z - mm1), f3 = __expf(va1.w - mm1);
            *(float4*)(gp1 + k0) = make_float4(f0 * ii1, f1 * ii1, f2 * ii1, f3 * ii1);
            u16x4 u1; u1[0] = f2bf(f0); u1[1] = f2bf(f1); u1[2] = f2bf(f2); u1[3] = f2bf(f3);
            *(u16x4*)((char*)As + ab1) = u1;
        }
        __syncthreads();   // barrier1: Bs DMA + As writes visible

        // ---- T14: issue next tile's M loads; they drain at barrier2,
        //      hidden under the ds_read+MFMA cluster below ------------------
        if (t + 1 < K_DIM / 64) {
            va0 = *(const float4*)(gp0 + k0 + 64);
            va1 = *(const float4*)(gp1 + k0 + 64);
        }

        // ---- MFMA: 2x4 tiles x 2 k-slices ----------------------------------
#pragma unroll
        for (int ks = 0; ks < 2; ++ks) {
            bf16x8 af[2], bfr[4];
#pragma unroll
            for (int tt = 0; tt < 2; ++tt) {
                const int arow = wm * 32 + tt * 16 + mr;
                const int ab = (arow * 128 + ks * 64 + kq16) ^ ((arow & 7) << 4);
                af[tt] = *(const bf16x8*)((const char*)As + ab);
            }
#pragma unroll
            for (int tt = 0; tt < 4; ++tt) {
                const int brow = wn * 64 + tt * 16 + mr;
                const int bb = (brow * 128 + ks * 64 + kq16) ^ ((brow & 7) << 4);
                bfr[tt] = *(const bf16x8*)((const char*)Bs + bb);
            }
#pragma unroll
            for (int i = 0; i < 2; ++i)
#pragma unroll
                for (int j = 0; j < 4; ++j)
                    acc[i][j] = __builtin_amdgcn_mfma_f32_16x16x32_bf16(
                        af[i], bfr[j], acc[i][j], 0, 0, 0);
        }
        __syncthreads();   // barrier2: As/Bs consumed (also drains prefetch)
    }

    // ---- epilogue: scale by 1/s, write C -----------------------------------
    const int col = lane & 15, rquad = (lane >> 4) * 4;
#pragma unroll
    for (int i = 0; i < 2; ++i) {
        const int lrow0 = wm * 32 + i * 16 + rquad;
#pragma unroll
        for (int j = 0; j < 4; ++j) {
            float* p = C + (m0 + lrow0) * (long)R_DIM + wn * 64 + j * 16 + col;
#pragma unroll
            for (int r = 0; r < 4; ++r)
                p[(long)r * R_DIM] = acc[i][j][r] * sm_inv[lrow0 + r];
        }
    }
}

// ===========================================================================
// Prep kernels
// ===========================================================================
// B' = [L_hi | L_lo | L_hi]  (K_DIM x 768)
__global__ __launch_bounds__(256)
void prep_B(const float* __restrict__ L, unsigned short* __restrict__ Bp)
{
    const long i = (long)blockIdx.x * 256 + threadIdx.x;   // over K_DIM*R_DIM
    const long k = i >> 8; const int r = (int)(i & 255);
    const float x = L[i];
    const unsigned short hi = f2bf(x);
    const unsigned short lo = f2bf(x - bf2f(hi));
    unsigned short* row = Bp + k * KP;
    row[r] = hi; row[R_DIM + r] = lo; row[2 * R_DIM + r] = hi;
}

// LT[r][k] = bf16(L[k][r])  (256 x 4096) — coalesced writes
__global__ __launch_bounds__(256)
void prep_LT(const float* __restrict__ L, unsigned short* __restrict__ LT)
{
    const long i = (long)blockIdx.x * 256 + threadIdx.x;   // over R_DIM*K_DIM
    const long r = i >> 12; const long k = i & 4095;
    LT[r * K_DIM + k] = f2bf(L[k * R_DIM + r]);
}

// ===========================================================================
// fp32 VALU GEMM — K1 base + fallback path.
// ===========================================================================
template<bool BT>
__global__ __launch_bounds__(256)
void gemm128(const float* __restrict__ A, const float* __restrict__ B,
             float* __restrict__ C, int M, int N, int Kc)
{
    __shared__ __align__(16) float Asl[16][132];
    __shared__ __align__(16) float Bsl[16][132];

    const int tid = threadIdx.x;
    const int tx = tid & 15, ty = tid >> 4;
    const long m0 = (long)blockIdx.x * 128;
    const long n0 = (long)blockIdx.y * 128;

    float acc[8][8];
#pragma unroll
    for (int i = 0; i < 8; ++i)
#pragma unroll
        for (int j = 0; j < 8; ++j) acc[i][j] = 0.f;

    for (int k0 = 0; k0 < Kc; k0 += 16) {
#pragma unroll
        for (int q = 0; q < 2; ++q) {
            int fi = tid + 256 * q, row = fi >> 2, col = (fi & 3) * 4;
            float4 v = *(const float4*)(A + (m0 + row) * (long)Kc + k0 + col);
            Asl[col + 0][row] = v.x; Asl[col + 1][row] = v.y;
            Asl[col + 2][row] = v.z; Asl[col + 3][row] = v.w;
        }
        if (BT) {
#pragma unroll
            for (int q = 0; q < 2; ++q) {
                int fi = tid + 256 * q, row = fi >> 2, col = (fi & 3) * 4;
                float4 v = *(const float4*)(B + (n0 + row) * (long)Kc + k0 + col);
                Bsl[col + 0][row] = v.x; Bsl[col + 1][row] = v.y;
                Bsl[col + 2][row] = v.z; Bsl[col + 3][row] = v.w;
            }
        } else {
#pragma unroll
            for (int q = 0; q < 2; ++q) {
                int fi = tid + 256 * q, row = fi >> 5, col = (fi & 31) * 4;
                float4 v = *(const float4*)(B + (k0 + row) * (long)N + n0 + col);
                *(float4*)&Bsl[row][col] = v;
            }
        }
        __syncthreads();
#pragma unroll
        for (int kk = 0; kk < 16; ++kk) {
            float a[8], b[8];
            *(float4*)&a[0] = *(const float4*)&Asl[kk][ty * 8];
            *(float4*)&a[4] = *(const float4*)&Asl[kk][ty * 8 + 4];
            *(float4*)&b[0] = *(const float4*)&Bsl[kk][tx * 8];
            *(float4*)&b[4] = *(const float4*)&Bsl[kk][tx * 8 + 4];
#pragma unroll
            for (int i = 0; i < 8; ++i)
#pragma unroll
                for (int j = 0; j < 8; ++j)
                    acc[i][j] = fmaf(a[i], b[j], acc[i][j]);
        }
        __syncthreads();
    }
#pragma unroll
    for (int i = 0; i < 8; ++i) {
        float* p = C + (m0 + ty * 8 + i) * (long)N + n0 + tx * 8;
        *(float4*)p       = make_float4(acc[i][0], acc[i][1], acc[i][2], acc[i][3]);
        *(float4*)(p + 4) = make_float4(acc[i][4], acc[i][5], acc[i][6], acc[i][7]);
    }
}

// ===========================================================================
// K1 with fused split-write: P = A@B (fp32 VALU), epilogue writes
// Ap = [P_hi | P_hi | P_lo] directly (no P materialization).
// ===========================================================================
__global__ __launch_bounds__(256)
void gemm128_hl(const float* __restrict__ A, const float* __restrict__ B,
                unsigned short* __restrict__ Ap, int M, int N, int Kc)
{
    __shared__ __align__(16) float Asl[16][132];
    __shared__ __align__(16) float Bsl[16][132];

    const int tid = threadIdx.x;
    const int tx = tid & 15, ty = tid >> 4;
    const long m0 = (long)blockIdx.x * 128;
    const long n0 = (long)blockIdx.y * 128;

    float acc[8][8];
#pragma unroll
    for (int i = 0; i < 8; ++i)
#pragma unroll
        for (int j = 0; j < 8; ++j) acc[i][j] = 0.f;

    for (int k0 = 0; k0 < Kc; k0 += 16) {
#pragma unroll
        for (int q = 0; q < 2; ++q) {
            int fi = tid + 256 * q, row = fi >> 2, col = (fi & 3) * 4;
            float4 v = *(const float4*)(A + (m0 + row) * (long)Kc + k0 + col);
            Asl[col + 0][row] = v.x; Asl[col + 1][row] = v.y;
            Asl[col + 2][row] = v.z; Asl[col + 3][row] = v.w;
        }
#pragma unroll
        for (int q = 0; q < 2; ++q) {
            int fi = tid + 256 * q, row = fi >> 5, col = (fi & 31) * 4;
            float4 v = *(const float4*)(B + (k0 + row) * (long)N + n0 + col);
            *(float4*)&Bsl[row][col] = v;
        }
        __syncthreads();
#pragma unroll
        for (int kk = 0; kk < 16; ++kk) {
            float a[8], b[8];
            *(float4*)&a[0] = *(const float4*)&Asl[kk][ty * 8];
            *(float4*)&a[4] = *(const float4*)&Asl[kk][ty * 8 + 4];
            *(float4*)&b[0] = *(const float4*)&Bsl[kk][tx * 8];
            *(float4*)&b[4] = *(const float4*)&Bsl[kk][tx * 8 + 4];
#pragma unroll
            for (int i = 0; i < 8; ++i)
#pragma unroll
                for (int j = 0; j < 8; ++j)
                    acc[i][j] = fmaf(a[i], b[j], acc[i][j]);
        }
        __syncthreads();
    }
#pragma unroll
    for (int i = 0; i < 8; ++i) {
        const long row = m0 + ty * 8 + i;
        const int  cb  = (int)n0 + tx * 8;
        u16x8 vh, vl;
#pragma unroll
        for (int j = 0; j < 8; ++j) {
            const float x = acc[i][j];
            const unsigned short hi = f2bf(x);
            vh[j] = hi;
            vl[j] = f2bf(x - bf2f(hi));
        }
        unsigned short* rp = Ap + row * KP;
        *(u16x8*)(rp + cb)             = vh;
        *(u16x8*)(rp + R_DIM + cb)     = vh;
        *(u16x8*)(rp + 2 * R_DIM + cb) = vl;
    }
}

// ---------------------------------------------------------------------------
// In-place row softmax (fallback path only)
// ---------------------------------------------------------------------------
__global__ __launch_bounds__(256)
void softmax_rows(float* __restrict__ Mio)
{
    const long n  = blockIdx.x;
    float* row    = Mio + n * (long)K_DIM;
    const int tid = threadIdx.x;

    float4 v[4];
    float lmax = -3.4e38f;
#pragma unroll
    for (int q = 0; q < 4; ++q) {
        v[q] = ((const float4*)row)[tid + 256 * q];
        lmax = fmaxf(lmax, fmaxf(fmaxf(v[q].x, v[q].y), fmaxf(v[q].z, v[q].w)));
    }
    __shared__ float redmax[4], redsum[4];
#pragma unroll
    for (int off = 32; off > 0; off >>= 1)
        lmax = fmaxf(lmax, __shfl_xor(lmax, off));
    if ((tid & 63) == 0) redmax[tid >> 6] = lmax;
    __syncthreads();
    const float gmax = fmaxf(fmaxf(redmax[0], redmax[1]), fmaxf(redmax[2], redmax[3]));

    float lsum = 0.f;
#pragma unroll
    for (int q = 0; q < 4; ++q) {
        v[q].x = __expf(v[q].x - gmax); v[q].y = __expf(v[q].y - gmax);
        v[q].z = __expf(v[q].z - gmax); v[q].w = __expf(v[q].w - gmax);
        lsum += v[q].x + v[q].y + v[q].z + v[q].w;
    }
#pragma unroll
    for (int off = 32; off > 0; off >>= 1)
        lsum += __shfl_xor(lsum, off);
    if ((tid & 63) == 0) redsum[tid >> 6] = lsum;
    __syncthreads();
    const float inv = 1.f / (redsum[0] + redsum[1] + redsum[2] + redsum[3]);
#pragma unroll
    for (int q = 0; q < 4; ++q) {
        v[q].x *= inv; v[q].y *= inv; v[q].z *= inv; v[q].w *= inv;
        ((float4*)row)[tid + 256 * q] = v[q];
    }
}

// ===========================================================================
extern "C" void kernel_launch(void* const* d_in, const int* in_sizes, int n_in,
                              void* d_out, int out_size, void* d_ws, size_t ws_size,
                              hipStream_t stream)
{
    const float* H  = (const float*)d_in[0];
    const float* L  = (const float*)d_in[1];
    const float* Wi = (const float*)d_in[2];

    float* Cout = (float*)d_out;                           // N x R
    float* Aout = (float*)d_out + (size_t)N_ROWS * R_DIM;  // N x K

    const size_t szAp = (size_t)N_ROWS * KP * 2;    // 48 MiB
    const size_t szBp = (size_t)K_DIM * KP * 2;     //  6 MiB
    const size_t szLT = (size_t)R_DIM * K_DIM * 2;  //  2 MiB
    const size_t szPm = (size_t)N_ROWS * KB * 4;    //  4 MiB
    const size_t szPs = (size_t)N_ROWS * KB * 4;    //  4 MiB
    const size_t szSM = (size_t)N_ROWS * 4;         // 128 KiB

    if (ws_size >= szAp + szBp + szLT + szPm + szPs + 2 * szSM) {
        char* w = (char*)d_ws;
        unsigned short* Ap = (unsigned short*)w;                 w += szAp;
        unsigned short* Bp = (unsigned short*)w;                 w += szBp;
        unsigned short* LT = (unsigned short*)w;                 w += szLT;
        float* Pm  = (float*)w;                                  w += szPm;
        float* Ps  = (float*)w;                                  w += szPs;
        float* SMm = (float*)w;                                  w += szSM;
        float* SMi = (float*)w;

        // K1: P = H@W_I (fp32 VALU), split [hi|hi|lo] written directly to Ap
        gemm128_hl<<<dim3(N_ROWS / 128, R_DIM / 128), 256, 0, stream>>>(
            H, Wi, Ap, N_ROWS, R_DIM, R_DIM);
        // Prep split B operand + transposed bf16 L
        prep_B<<<dim3((K_DIM * R_DIM) / 256), 256, 0, stream>>>(L, Bp);
        prep_LT<<<dim3((R_DIM * K_DIM) / 256), 256, 0, stream>>>(L, LT);
        // K2: logits M = A'·B'^T (3-term split bf16 MFMA) + softmax partials
        // 1-D grid with 32x32 super-block traversal for L2 residency
        gemm_mfma_nt<<<dim3((N_ROWS / 128) * (K_DIM / 128)), 256, 0, stream>>>(
            Ap, Bp, Aout, Pm, Ps, N_ROWS, K_DIM, KP);
        // combine partials -> per-row (max, 1/sum)
        finalize_ms<<<dim3(N_ROWS / 256), 256, 0, stream>>>(Pm, Ps, SMm, SMi);
        // fused softmax-apply + PV (T14 prefetch)
        softmax_av_pv<<<dim3(N_ROWS / 64), 512, 0, stream>>>(
            Aout, LT, SMm, SMi, Cout);
    } else {
        // Fallback: round-1 fp32 path
        gemm128<false><<<dim3(N_ROWS / 128, R_DIM / 128), 256, 0, stream>>>(
            H, Wi, Cout, N_ROWS, R_DIM, R_DIM);
        gemm128<true><<<dim3(N_ROWS / 128, K_DIM / 128), 256, 0, stream>>>(
            Cout, L, Aout, N_ROWS, K_DIM, R_DIM);
        softmax_rows<<<dim3(N_ROWS), 256, 0, stream>>>(Aout);
        gemm128<false><<<dim3(N_ROWS / 128, R_DIM / 128), 256, 0, stream>>>(
            Aout, L, Cout, N_ROWS, R_DIM, K_DIM);
    }
}

// Round 7
// 1149.701 us; speedup vs baseline: 1.2601x; 1.0478x over previous
//
#include <hip/hip_runtime.h>
#include <hip/hip_bf16.h>
#include <math.h>
#include <stdint.h>

// Problem constants
constexpr int N_ROWS = 32768;
constexpr int K_DIM  = 4096;
constexpr int R_DIM  = 256;
constexpr int KP     = 3 * R_DIM;   // 768: split-K' for [hi|hi|lo] x [hi|lo|hi]
constexpr int KB     = K_DIM / 128; // 32 col-blocks in K2 grid

typedef __bf16 bf16x8 __attribute__((ext_vector_type(8)));
typedef float  f32x4  __attribute__((ext_vector_type(4)));
typedef unsigned short u16x8 __attribute__((ext_vector_type(8)));
typedef unsigned short u16x4 __attribute__((ext_vector_type(4)));

// ---- bf16 helpers (round-to-nearest-even; inputs are finite normals) ----
__device__ __forceinline__ unsigned short f2bf(float x) {
    unsigned u = __float_as_uint(x);
    u += 0x7fffu + ((u >> 16) & 1u);
    return (unsigned short)(u >> 16);
}
__device__ __forceinline__ float bf2f(unsigned short h) {
    return __uint_as_float((unsigned)h << 16);
}

// ---- async global->LDS, 16B per lane, LDS dest = wave-uniform base + lane*16
__device__ __forceinline__ void gl2lds16(const void* gptr, void* lptr) {
    __builtin_amdgcn_global_load_lds(
        (const __attribute__((address_space(1))) unsigned int*)gptr,
        (__attribute__((address_space(3))) unsigned int*)lptr,
        16, 0, 0);
}

// ===========================================================================
// K2: logits over A'(bf16 split) x B'^T. 128x128 tile, BK=32, 4 waves.
// Grid: 1-D super-block traversal (R6-proven: A-panel stays L2-resident).
// Epilogue: per-row softmax partials (Pm/Ps) AND e16 = bf16(exp(x - m_blk))
// written into the UPPER HALF of each output row's fp32 span in Aout
// (ushort idx r*8192 + 4096 + k). No fp32 M is materialized: av_pv rebuilds
// A = e16 * exp(m_blk - m_row) * inv_row. Halves K2 writes + av_pv reads.
// ===========================================================================
__global__ __launch_bounds__(256)
void gemm_mfma_nt(const unsigned short* __restrict__ A,
                  const unsigned short* __restrict__ B,
                  float* __restrict__ Mout,
                  float* __restrict__ Pm, float* __restrict__ Ps,
                  int M, int N, int Kc)
{
    __shared__ __align__(16) unsigned short As[128 * 32];
    __shared__ __align__(16) unsigned short Bs[128 * 32];
    __shared__ float pm_s[128][2], ps_s[128][2];
    __shared__ float pmc[128];

    const int tid  = threadIdx.x;
    const int wave = tid >> 6, lane = tid & 63;
    const int wm = wave >> 1, wn = wave & 1;

    // bijective 1-D decode: bid = xg*1024 + y*32 + xi
    const int bid = blockIdx.x;
    const int xg = bid >> 10;          // row super-group 0..7
    const int yb = (bid >> 5) & 31;    // col-panel     0..31
    const int xi = bid & 31;           // row-panel within group
    const long m0 = (long)(xg * 32 + xi) * 128;
    const long n0 = (long)yb * 128;

    f32x4 acc[4][4] = {};

    const int srow  = lane >> 2;        // 0..15 within 16-row chunk
    const int skoff = (lane & 3) * 8;   // bf16 elem offset within 32-wide row
    const int c0 = wave, c1 = wave + 4; // each wave stages 2 chunks per tile
    const int kq = (lane >> 4) * 8;     // frag k-offset 0,8,16,24
    const int mr = lane & 15;

    for (int k0 = 0; k0 < Kc; k0 += 32) {
        gl2lds16(A + (m0 + c0 * 16 + srow) * (long)Kc + k0 + skoff, &As[c0 * 512]);
        gl2lds16(A + (m0 + c1 * 16 + srow) * (long)Kc + k0 + skoff, &As[c1 * 512]);
        gl2lds16(B + (n0 + c0 * 16 + srow) * (long)Kc + k0 + skoff, &Bs[c0 * 512]);
        gl2lds16(B + (n0 + c1 * 16 + srow) * (long)Kc + k0 + skoff, &Bs[c1 * 512]);
        __syncthreads();

        bf16x8 af[4], bfr[4];
#pragma unroll
        for (int t = 0; t < 4; ++t) {
            af[t]  = *(const bf16x8*)&As[(wm * 64 + t * 16 + mr) * 32 + kq];
            bfr[t] = *(const bf16x8*)&Bs[(wn * 64 + t * 16 + mr) * 32 + kq];
        }
#pragma unroll
        for (int i = 0; i < 4; ++i)
#pragma unroll
            for (int j = 0; j < 4; ++j)
                acc[i][j] = __builtin_amdgcn_mfma_f32_16x16x32_bf16(
                    af[i], bfr[j], acc[i][j], 0, 0, 0);
        __syncthreads();
    }

    const int col = lane & 15, rquad = (lane >> 4) * 4;

    // ---- softmax partials over this block's 128 cols, per row --------------
#pragma unroll
    for (int i = 0; i < 4; ++i) {
#pragma unroll
        for (int r = 0; r < 4; ++r) {
            float mx = fmaxf(fmaxf(acc[i][0][r], acc[i][1][r]),
                             fmaxf(acc[i][2][r], acc[i][3][r]));
#pragma unroll
            for (int off = 1; off < 16; off <<= 1)
                mx = fmaxf(mx, __shfl_xor(mx, off));
            float sm = 0.f;
#pragma unroll
            for (int j = 0; j < 4; ++j) sm += __expf(acc[i][j][r] - mx);
#pragma unroll
            for (int off = 1; off < 16; off <<= 1)
                sm += __shfl_xor(sm, off);
            if (mr == 0) {
                const int rw = wm * 64 + i * 16 + rquad + r;
                pm_s[rw][wn] = mx;
                ps_s[rw][wn] = sm;
            }
        }
    }
    __syncthreads();
    if (tid < 128) {
        const float ma = pm_s[tid][0], mb = pm_s[tid][1];
        const float mx = fmaxf(ma, mb);
        const float s  = ps_s[tid][0] * __expf(ma - mx) +
                         ps_s[tid][1] * __expf(mb - mx);
        pmc[tid] = mx;
        Pm[(m0 + tid) * KB + yb] = mx;
        Ps[(m0 + tid) * KB + yb] = s;
    }
    __syncthreads();

    // ---- e16 write: bf16(exp(acc - m_blk)) into upper half of row span -----
    unsigned short* E = (unsigned short*)Mout;
#pragma unroll
    for (int i = 0; i < 4; ++i) {
#pragma unroll
        for (int r = 0; r < 4; ++r) {
            const int rw = wm * 64 + i * 16 + rquad + r;
            const float mx = pmc[rw];
            unsigned short* ep =
                E + (m0 + rw) * 8192L + 4096 + n0 + wn * 64 + col;
#pragma unroll
            for (int j = 0; j < 4; ++j)
                ep[j * 16] = f2bf(__expf(acc[i][j][r] - mx));
        }
    }
}

// ===========================================================================
// Combine per-block softmax partials -> per-row (max, 1/sum).
// ===========================================================================
__global__ __launch_bounds__(256)
void finalize_ms(const float* __restrict__ Pm, const float* __restrict__ Ps,
                 float* __restrict__ SMm, float* __restrict__ SMi)
{
    const long row = (long)blockIdx.x * 256 + threadIdx.x;
    const float4* pm = (const float4*)(Pm + row * KB);
    const float4* ps = (const float4*)(Ps + row * KB);
    float4 v[8];
    float mx = -3.4e38f;
#pragma unroll
    for (int q = 0; q < 8; ++q) {
        v[q] = pm[q];
        mx = fmaxf(mx, fmaxf(fmaxf(v[q].x, v[q].y), fmaxf(v[q].z, v[q].w)));
    }
    float s = 0.f;
#pragma unroll
    for (int q = 0; q < 8; ++q) {
        float4 w = ps[q];
        s += w.x * __expf(v[q].x - mx) + w.y * __expf(v[q].y - mx) +
             w.z * __expf(v[q].z - mx) + w.w * __expf(v[q].w - mx);
    }
    SMm[row] = mx;
    SMi[row] = 1.f / s;
}

// ===========================================================================
// Fused softmax-apply + PV from e16:
//   A[n,k] = bf2f(e16[n,k]) * cs[n][k/128]   (fp32, written over Aout rows)
//   C[n,r] = sum_k A[n,k] * LT[r,k]          (bf16 MFMA, A already normalized)
// cs[n][b] = exp(Pm[n][b] - m_n) * inv_n precomputed into LDS.
// Aliasing: e16 lives in the upper half of each row's span; A-writes at k
// clobber e16 at k' = 2k-4096 (consumed for t<63); extra barrier at t=63.
// Grid: N_ROWS/64 x 512 threads (8 waves). T14 prefetch as in R6.
// ===========================================================================
__global__ __launch_bounds__(512)
void softmax_av_pv(float* Aout,                      // NOT restrict: aliases e16
                   const unsigned short* __restrict__ LT,
                   const float* __restrict__ Pm,
                   const float* __restrict__ SMm,
                   const float* __restrict__ SMi,
                   float* __restrict__ C)
{
    __shared__ __align__(16) unsigned short Bs[R_DIM * 64]; // 32 KiB (swizzled)
    __shared__ __align__(16) unsigned short As[64 * 64];    //  8 KiB (swizzled)
    __shared__ float cs[64][32];                            //  8 KiB

    const int tid  = threadIdx.x;
    const int wave = tid >> 6, lane = tid & 63;
    const long m0 = (long)blockIdx.x * 64;

    // per-(row, 128-col-block) rescale factors
    {
        const int i0 = tid * 4;            // 2048 = 64 rows x 32 blocks
        const int r  = i0 >> 5;
        const int b  = i0 & 31;
        const float m = SMm[m0 + r], inv = SMi[m0 + r];
        const float4 pv = *(const float4*)(Pm + (m0 + r) * KB + b);
        cs[r][b + 0] = __expf(pv.x - m) * inv;
        cs[r][b + 1] = __expf(pv.y - m) * inv;
        cs[r][b + 2] = __expf(pv.z - m) * inv;
        cs[r][b + 3] = __expf(pv.w - m) * inv;
    }
    __syncthreads();

    f32x4 acc[2][4] = {};
    const int wm = wave >> 2, wn = wave & 3;  // wave tile: 32 rows x 64 cols
    const int mr = lane & 15;
    const int kq16 = (lane >> 4) * 16;

    // A-emit mapping: each thread owns 2 rows, 4 cols
    const int arow0 = wave * 4 + (lane >> 4);
    const int arow1 = 32 + arow0;
    const int acolE = (lane & 15) * 4;
    const unsigned short* const ep0 =
        (const unsigned short*)Aout + (m0 + arow0) * 8192L + 4096 + acolE;
    const unsigned short* const ep1 =
        (const unsigned short*)Aout + (m0 + arow1) * 8192L + 4096 + acolE;
    float* const gp0 = Aout + (m0 + arow0) * (long)K_DIM + acolE;
    float* const gp1 = Aout + (m0 + arow1) * (long)K_DIM + acolE;
    const int ab0 = (arow0 * 128 + acolE * 2) ^ ((arow0 & 7) << 4);
    const int ab1 = (arow1 * 128 + acolE * 2) ^ ((arow1 & 7) << 4);

    // prologue: prefetch tile 0's e16
    u16x4 va0 = *(const u16x4*)ep0;
    u16x4 va1 = *(const u16x4*)ep1;

    constexpr int NT = K_DIM / 64;
    for (int t = 0; t < NT; ++t) {
        const int k0 = t * 64;
        // final tile: drain all waves' e16 prefetch before A-writes can
        // clobber the aliased tail (k'=2k-4096 overlaps in-flight reads
        // only at t=63 — see header comment)
        if (t == NT - 1) __syncthreads();

        // ---- stage LT tile (256 r x 64 k) via async DMA, source pre-swizzled
#pragma unroll
        for (int q = 0; q < 4; ++q) {
            const int rbase = q * 64 + wave * 8;
            const int rloc  = rbase + (lane >> 3);
            const int phys  = (lane & 7) * 16;
            const int kbyte = phys ^ ((rloc & 7) << 4);
            gl2lds16((const char*)LT + (long)rloc * (K_DIM * 2) + (long)k0 * 2 + kbyte,
                     &Bs[rbase * 64]);
        }
        // ---- emit tile t from prefetched e16: scale, A-write, LDS bf16 -----
        {
            const float c0 = cs[arow0][t >> 1], c1 = cs[arow1][t >> 1];
            float a0 = bf2f(va0[0]) * c0, a1 = bf2f(va0[1]) * c0;
            float a2 = bf2f(va0[2]) * c0, a3 = bf2f(va0[3]) * c0;
            *(float4*)(gp0 + k0) = make_float4(a0, a1, a2, a3);
            u16x4 u0;
            u0[0] = f2bf(a0); u0[1] = f2bf(a1); u0[2] = f2bf(a2); u0[3] = f2bf(a3);
            *(u16x4*)((char*)As + ab0) = u0;

            float b0 = bf2f(va1[0]) * c1, b1 = bf2f(va1[1]) * c1;
            float b2 = bf2f(va1[2]) * c1, b3 = bf2f(va1[3]) * c1;
            *(float4*)(gp1 + k0) = make_float4(b0, b1, b2, b3);
            u16x4 u1;
            u1[0] = f2bf(b0); u1[1] = f2bf(b1); u1[2] = f2bf(b2); u1[3] = f2bf(b3);
            *(u16x4*)((char*)As + ab1) = u1;
        }
        __syncthreads();   // barrier1: Bs DMA + As writes visible

        // ---- T14: next tile's e16 loads drain under the MFMA cluster -------
        if (t + 1 < NT) {
            va0 = *(const u16x4*)(ep0 + (t + 1) * 64);
            va1 = *(const u16x4*)(ep1 + (t + 1) * 64);
        }

        // ---- MFMA: 2x4 tiles x 2 k-slices ----------------------------------
#pragma unroll
        for (int ks = 0; ks < 2; ++ks) {
            bf16x8 af[2], bfr[4];
#pragma unroll
            for (int tt = 0; tt < 2; ++tt) {
                const int arow = wm * 32 + tt * 16 + mr;
                const int ab = (arow * 128 + ks * 64 + kq16) ^ ((arow & 7) << 4);
                af[tt] = *(const bf16x8*)((const char*)As + ab);
            }
#pragma unroll
            for (int tt = 0; tt < 4; ++tt) {
                const int brow = wn * 64 + tt * 16 + mr;
                const int bb = (brow * 128 + ks * 64 + kq16) ^ ((brow & 7) << 4);
                bfr[tt] = *(const bf16x8*)((const char*)Bs + bb);
            }
#pragma unroll
            for (int i = 0; i < 2; ++i)
#pragma unroll
                for (int j = 0; j < 4; ++j)
                    acc[i][j] = __builtin_amdgcn_mfma_f32_16x16x32_bf16(
                        af[i], bfr[j], acc[i][j], 0, 0, 0);
        }
        __syncthreads();   // barrier2
    }

    // ---- epilogue: A was already normalized -> C = acc directly ------------
    const int col = lane & 15, rquad = (lane >> 4) * 4;
#pragma unroll
    for (int i = 0; i < 2; ++i) {
        const int lrow0 = wm * 32 + i * 16 + rquad;
#pragma unroll
        for (int j = 0; j < 4; ++j) {
            float* p = C + (m0 + lrow0) * (long)R_DIM + wn * 64 + j * 16 + col;
#pragma unroll
            for (int r = 0; r < 4; ++r)
                p[(long)r * R_DIM] = acc[i][j][r];
        }
    }
}

// ===========================================================================
// Prep kernels
// ===========================================================================
// B' = [L_hi | L_lo | L_hi]  (K_DIM x 768)
__global__ __launch_bounds__(256)
void prep_B(const float* __restrict__ L, unsigned short* __restrict__ Bp)
{
    const long i = (long)blockIdx.x * 256 + threadIdx.x;   // over K_DIM*R_DIM
    const long k = i >> 8; const int r = (int)(i & 255);
    const float x = L[i];
    const unsigned short hi = f2bf(x);
    const unsigned short lo = f2bf(x - bf2f(hi));
    unsigned short* row = Bp + k * KP;
    row[r] = hi; row[R_DIM + r] = lo; row[2 * R_DIM + r] = hi;
}

// LT[r][k] = bf16(L[k][r])  (256 x 4096) — coalesced writes
__global__ __launch_bounds__(256)
void prep_LT(const float* __restrict__ L, unsigned short* __restrict__ LT)
{
    const long i = (long)blockIdx.x * 256 + threadIdx.x;   // over R_DIM*K_DIM
    const long r = i >> 12; const long k = i & 4095;
    LT[r * K_DIM + k] = f2bf(L[k * R_DIM + r]);
}

// ===========================================================================
// fp32 VALU GEMM — K1 base + fallback path.
// ===========================================================================
template<bool BT>
__global__ __launch_bounds__(256)
void gemm128(const float* __restrict__ A, const float* __restrict__ B,
             float* __restrict__ C, int M, int N, int Kc)
{
    __shared__ __align__(16) float Asl[16][132];
    __shared__ __align__(16) float Bsl[16][132];

    const int tid = threadIdx.x;
    const int tx = tid & 15, ty = tid >> 4;
    const long m0 = (long)blockIdx.x * 128;
    const long n0 = (long)blockIdx.y * 128;

    float acc[8][8];
#pragma unroll
    for (int i = 0; i < 8; ++i)
#pragma unroll
        for (int j = 0; j < 8; ++j) acc[i][j] = 0.f;

    for (int k0 = 0; k0 < Kc; k0 += 16) {
#pragma unroll
        for (int q = 0; q < 2; ++q) {
            int fi = tid + 256 * q, row = fi >> 2, col = (fi & 3) * 4;
            float4 v = *(const float4*)(A + (m0 + row) * (long)Kc + k0 + col);
            Asl[col + 0][row] = v.x; Asl[col + 1][row] = v.y;
            Asl[col + 2][row] = v.z; Asl[col + 3][row] = v.w;
        }
        if (BT) {
#pragma unroll
            for (int q = 0; q < 2; ++q) {
                int fi = tid + 256 * q, row = fi >> 2, col = (fi & 3) * 4;
                float4 v = *(const float4*)(B + (n0 + row) * (long)Kc + k0 + col);
                Bsl[col + 0][row] = v.x; Bsl[col + 1][row] = v.y;
                Bsl[col + 2][row] = v.z; Bsl[col + 3][row] = v.w;
            }
        } else {
#pragma unroll
            for (int q = 0; q < 2; ++q) {
                int fi = tid + 256 * q, row = fi >> 5, col = (fi & 31) * 4;
                float4 v = *(const float4*)(B + (k0 + row) * (long)N + n0 + col);
                *(float4*)&Bsl[row][col] = v;
            }
        }
        __syncthreads();
#pragma unroll
        for (int kk = 0; kk < 16; ++kk) {
            float a[8], b[8];
            *(float4*)&a[0] = *(const float4*)&Asl[kk][ty * 8];
            *(float4*)&a[4] = *(const float4*)&Asl[kk][ty * 8 + 4];
            *(float4*)&b[0] = *(const float4*)&Bsl[kk][tx * 8];
            *(float4*)&b[4] = *(const float4*)&Bsl[kk][tx * 8 + 4];
#pragma unroll
            for (int i = 0; i < 8; ++i)
#pragma unroll
                for (int j = 0; j < 8; ++j)
                    acc[i][j] = fmaf(a[i], b[j], acc[i][j]);
        }
        __syncthreads();
    }
#pragma unroll
    for (int i = 0; i < 8; ++i) {
        float* p = C + (m0 + ty * 8 + i) * (long)N + n0 + tx * 8;
        *(float4*)p       = make_float4(acc[i][0], acc[i][1], acc[i][2], acc[i][3]);
        *(float4*)(p + 4) = make_float4(acc[i][4], acc[i][5], acc[i][6], acc[i][7]);
    }
}

// ===========================================================================
// K1 with fused split-write: P = A@B (fp32 VALU), epilogue writes
// Ap = [P_hi | P_hi | P_lo] directly (no P materialization).
// ===========================================================================
__global__ __launch_bounds__(256)
void gemm128_hl(const float* __restrict__ A, const float* __restrict__ B,
                unsigned short* __restrict__ Ap, int M, int N, int Kc)
{
    __shared__ __align__(16) float Asl[16][132];
    __shared__ __align__(16) float Bsl[16][132];

    const int tid = threadIdx.x;
    const int tx = tid & 15, ty = tid >> 4;
    const long m0 = (long)blockIdx.x * 128;
    const long n0 = (long)blockIdx.y * 128;

    float acc[8][8];
#pragma unroll
    for (int i = 0; i < 8; ++i)
#pragma unroll
        for (int j = 0; j < 8; ++j) acc[i][j] = 0.f;

    for (int k0 = 0; k0 < Kc; k0 += 16) {
#pragma unroll
        for (int q = 0; q < 2; ++q) {
            int fi = tid + 256 * q, row = fi >> 2, col = (fi & 3) * 4;
            float4 v = *(const float4*)(A + (m0 + row) * (long)Kc + k0 + col);
            Asl[col + 0][row] = v.x; Asl[col + 1][row] = v.y;
            Asl[col + 2][row] = v.z; Asl[col + 3][row] = v.w;
        }
#pragma unroll
        for (int q = 0; q < 2; ++q) {
            int fi = tid + 256 * q, row = fi >> 5, col = (fi & 31) * 4;
            float4 v = *(const float4*)(B + (k0 + row) * (long)N + n0 + col);
            *(float4*)&Bsl[row][col] = v;
        }
        __syncthreads();
#pragma unroll
        for (int kk = 0; kk < 16; ++kk) {
            float a[8], b[8];
            *(float4*)&a[0] = *(const float4*)&Asl[kk][ty * 8];
            *(float4*)&a[4] = *(const float4*)&Asl[kk][ty * 8 + 4];
            *(float4*)&b[0] = *(const float4*)&Bsl[kk][tx * 8];
            *(float4*)&b[4] = *(const float4*)&Bsl[kk][tx * 8 + 4];
#pragma unroll
            for (int i = 0; i < 8; ++i)
#pragma unroll
                for (int j = 0; j < 8; ++j)
                    acc[i][j] = fmaf(a[i], b[j], acc[i][j]);
        }
        __syncthreads();
    }
#pragma unroll
    for (int i = 0; i < 8; ++i) {
        const long row = m0 + ty * 8 + i;
        const int  cb  = (int)n0 + tx * 8;
        u16x8 vh, vl;
#pragma unroll
        for (int j = 0; j < 8; ++j) {
            const float x = acc[i][j];
            const unsigned short hi = f2bf(x);
            vh[j] = hi;
            vl[j] = f2bf(x - bf2f(hi));
        }
        unsigned short* rp = Ap + row * KP;
        *(u16x8*)(rp + cb)             = vh;
        *(u16x8*)(rp + R_DIM + cb)     = vh;
        *(u16x8*)(rp + 2 * R_DIM + cb) = vl;
    }
}

// ---------------------------------------------------------------------------
// In-place row softmax (fallback path only)
// ---------------------------------------------------------------------------
__global__ __launch_bounds__(256)
void softmax_rows(float* __restrict__ Mio)
{
    const long n  = blockIdx.x;
    float* row    = Mio + n * (long)K_DIM;
    const int tid = threadIdx.x;

    float4 v[4];
    float lmax = -3.4e38f;
#pragma unroll
    for (int q = 0; q < 4; ++q) {
        v[q] = ((const float4*)row)[tid + 256 * q];
        lmax = fmaxf(lmax, fmaxf(fmaxf(v[q].x, v[q].y), fmaxf(v[q].z, v[q].w)));
    }
    __shared__ float redmax[4], redsum[4];
#pragma unroll
    for (int off = 32; off > 0; off >>= 1)
        lmax = fmaxf(lmax, __shfl_xor(lmax, off));
    if ((tid & 63) == 0) redmax[tid >> 6] = lmax;
    __syncthreads();
    const float gmax = fmaxf(fmaxf(redmax[0], redmax[1]), fmaxf(redmax[2], redmax[3]));

    float lsum = 0.f;
#pragma unroll
    for (int q = 0; q < 4; ++q) {
        v[q].x = __expf(v[q].x - gmax); v[q].y = __expf(v[q].y - gmax);
        v[q].z = __expf(v[q].z - gmax); v[q].w = __expf(v[q].w - gmax);
        lsum += v[q].x + v[q].y + v[q].z + v[q].w;
    }
#pragma unroll
    for (int off = 32; off > 0; off >>= 1)
        lsum += __shfl_xor(lsum, off);
    if ((tid & 63) == 0) redsum[tid >> 6] = lsum;
    __syncthreads();
    const float inv = 1.f / (redsum[0] + redsum[1] + redsum[2] + redsum[3]);
#pragma unroll
    for (int q = 0; q < 4; ++q) {
        v[q].x *= inv; v[q].y *= inv; v[q].z *= inv; v[q].w *= inv;
        ((float4*)row)[tid + 256 * q] = v[q];
    }
}

// ===========================================================================
extern "C" void kernel_launch(void* const* d_in, const int* in_sizes, int n_in,
                              void* d_out, int out_size, void* d_ws, size_t ws_size,
                              hipStream_t stream)
{
    const float* H  = (const float*)d_in[0];
    const float* L  = (const float*)d_in[1];
    const float* Wi = (const float*)d_in[2];

    float* Cout = (float*)d_out;                           // N x R
    float* Aout = (float*)d_out + (size_t)N_ROWS * R_DIM;  // N x K

    const size_t szAp = (size_t)N_ROWS * KP * 2;    // 48 MiB
    const size_t szBp = (size_t)K_DIM * KP * 2;     //  6 MiB
    const size_t szLT = (size_t)R_DIM * K_DIM * 2;  //  2 MiB
    const size_t szPm = (size_t)N_ROWS * KB * 4;    //  4 MiB
    const size_t szPs = (size_t)N_ROWS * KB * 4;    //  4 MiB
    const size_t szSM = (size_t)N_ROWS * 4;         // 128 KiB

    if (ws_size >= szAp + szBp + szLT + szPm + szPs + 2 * szSM) {
        char* w = (char*)d_ws;
        unsigned short* Ap = (unsigned short*)w;                 w += szAp;
        unsigned short* Bp = (unsigned short*)w;                 w += szBp;
        unsigned short* LT = (unsigned short*)w;                 w += szLT;
        float* Pm  = (float*)w;                                  w += szPm;
        float* Ps  = (float*)w;                                  w += szPs;
        float* SMm = (float*)w;                                  w += szSM;
        float* SMi = (float*)w;

        // K1: P = H@W_I (fp32 VALU), split [hi|hi|lo] written directly to Ap
        gemm128_hl<<<dim3(N_ROWS / 128, R_DIM / 128), 256, 0, stream>>>(
            H, Wi, Ap, N_ROWS, R_DIM, R_DIM);
        // Prep split B operand + transposed bf16 L
        prep_B<<<dim3((K_DIM * R_DIM) / 256), 256, 0, stream>>>(L, Bp);
        prep_LT<<<dim3((R_DIM * K_DIM) / 256), 256, 0, stream>>>(L, LT);
        // K2: logits (3-term split bf16 MFMA) -> e16 + softmax partials
        gemm_mfma_nt<<<dim3((N_ROWS / 128) * (K_DIM / 128)), 256, 0, stream>>>(
            Ap, Bp, Aout, Pm, Ps, N_ROWS, K_DIM, KP);
        // combine partials -> per-row (max, 1/sum)
        finalize_ms<<<dim3(N_ROWS / 256), 256, 0, stream>>>(Pm, Ps, SMm, SMi);
        // fused softmax-apply + PV from e16 (half the read traffic, no exp)
        softmax_av_pv<<<dim3(N_ROWS / 64), 512, 0, stream>>>(
            Aout, LT, Pm, SMm, SMi, Cout);
    } else {
        // Fallback: round-1 fp32 path
        gemm128<false><<<dim3(N_ROWS / 128, R_DIM / 128), 256, 0, stream>>>(
            H, Wi, Cout, N_ROWS, R_DIM, R_DIM);
        gemm128<true><<<dim3(N_ROWS / 128, K_DIM / 128), 256, 0, stream>>>(
            Cout, L, Aout, N_ROWS, K_DIM, R_DIM);
        softmax_rows<<<dim3(N_ROWS), 256, 0, stream>>>(Aout);
        gemm128<false><<<dim3(N_ROWS / 128, R_DIM / 128), 256, 0, stream>>>(
            Aout, L, Cout, N_ROWS, R_DIM, K_DIM);
    }
}

// Round 8
// 1147.719 us; speedup vs baseline: 1.2623x; 1.0017x over previous
//
#include <hip/hip_runtime.h>
#include <hip/hip_bf16.h>
#include <math.h>
#include <stdint.h>

// Problem constants
constexpr int N_ROWS = 32768;
constexpr int K_DIM  = 4096;
constexpr int R_DIM  = 256;
constexpr int KP     = 3 * R_DIM;   // 768: split-K' for [hi|hi|lo] x [hi|lo|hi]
constexpr int KB     = K_DIM / 128; // 32 col-blocks in K2 grid

typedef __bf16 bf16x8 __attribute__((ext_vector_type(8)));
typedef float  f32x4  __attribute__((ext_vector_type(4)));
typedef unsigned short u16x8 __attribute__((ext_vector_type(8)));
typedef unsigned short u16x4 __attribute__((ext_vector_type(4)));

// ---- bf16 helpers (round-to-nearest-even; inputs are finite normals) ----
__device__ __forceinline__ unsigned short f2bf(float x) {
    unsigned u = __float_as_uint(x);
    u += 0x7fffu + ((u >> 16) & 1u);
    return (unsigned short)(u >> 16);
}
__device__ __forceinline__ float bf2f(unsigned short h) {
    return __uint_as_float((unsigned)h << 16);
}

// ---- async global->LDS, 16B per lane, LDS dest = wave-uniform base + lane*16
__device__ __forceinline__ void gl2lds16(const void* gptr, void* lptr) {
    __builtin_amdgcn_global_load_lds(
        (const __attribute__((address_space(1))) unsigned int*)gptr,
        (__attribute__((address_space(3))) unsigned int*)lptr,
        16, 0, 0);
}

// ===========================================================================
// K2: logits over A'(bf16 split) x B'^T. 128x128 tile, BK=32, 4 waves.
// Grid: 1-D super-block traversal (R6-proven: A-panel stays L2-resident).
// Epilogue: per-row softmax partials (Pm/Ps) AND e16 = bf16(exp(x - m_blk))
// written into the UPPER HALF of each output row's fp32 span in Aout.
// (R7-proven, unchanged.)
// ===========================================================================
__global__ __launch_bounds__(256)
void gemm_mfma_nt(const unsigned short* __restrict__ A,
                  const unsigned short* __restrict__ B,
                  float* __restrict__ Mout,
                  float* __restrict__ Pm, float* __restrict__ Ps,
                  int M, int N, int Kc)
{
    __shared__ __align__(16) unsigned short As[128 * 32];
    __shared__ __align__(16) unsigned short Bs[128 * 32];
    __shared__ float pm_s[128][2], ps_s[128][2];
    __shared__ float pmc[128];

    const int tid  = threadIdx.x;
    const int wave = tid >> 6, lane = tid & 63;
    const int wm = wave >> 1, wn = wave & 1;

    // bijective 1-D decode: bid = xg*1024 + y*32 + xi
    const int bid = blockIdx.x;
    const int xg = bid >> 10;          // row super-group 0..7
    const int yb = (bid >> 5) & 31;    // col-panel     0..31
    const int xi = bid & 31;           // row-panel within group
    const long m0 = (long)(xg * 32 + xi) * 128;
    const long n0 = (long)yb * 128;

    f32x4 acc[4][4] = {};

    const int srow  = lane >> 2;        // 0..15 within 16-row chunk
    const int skoff = (lane & 3) * 8;   // bf16 elem offset within 32-wide row
    const int c0 = wave, c1 = wave + 4; // each wave stages 2 chunks per tile
    const int kq = (lane >> 4) * 8;     // frag k-offset 0,8,16,24
    const int mr = lane & 15;

    for (int k0 = 0; k0 < Kc; k0 += 32) {
        gl2lds16(A + (m0 + c0 * 16 + srow) * (long)Kc + k0 + skoff, &As[c0 * 512]);
        gl2lds16(A + (m0 + c1 * 16 + srow) * (long)Kc + k0 + skoff, &As[c1 * 512]);
        gl2lds16(B + (n0 + c0 * 16 + srow) * (long)Kc + k0 + skoff, &Bs[c0 * 512]);
        gl2lds16(B + (n0 + c1 * 16 + srow) * (long)Kc + k0 + skoff, &Bs[c1 * 512]);
        __syncthreads();

        bf16x8 af[4], bfr[4];
#pragma unroll
        for (int t = 0; t < 4; ++t) {
            af[t]  = *(const bf16x8*)&As[(wm * 64 + t * 16 + mr) * 32 + kq];
            bfr[t] = *(const bf16x8*)&Bs[(wn * 64 + t * 16 + mr) * 32 + kq];
        }
#pragma unroll
        for (int i = 0; i < 4; ++i)
#pragma unroll
            for (int j = 0; j < 4; ++j)
                acc[i][j] = __builtin_amdgcn_mfma_f32_16x16x32_bf16(
                    af[i], bfr[j], acc[i][j], 0, 0, 0);
        __syncthreads();
    }

    const int col = lane & 15, rquad = (lane >> 4) * 4;

    // ---- softmax partials over this block's 128 cols, per row --------------
#pragma unroll
    for (int i = 0; i < 4; ++i) {
#pragma unroll
        for (int r = 0; r < 4; ++r) {
            float mx = fmaxf(fmaxf(acc[i][0][r], acc[i][1][r]),
                             fmaxf(acc[i][2][r], acc[i][3][r]));
#pragma unroll
            for (int off = 1; off < 16; off <<= 1)
                mx = fmaxf(mx, __shfl_xor(mx, off));
            float sm = 0.f;
#pragma unroll
            for (int j = 0; j < 4; ++j) sm += __expf(acc[i][j][r] - mx);
#pragma unroll
            for (int off = 1; off < 16; off <<= 1)
                sm += __shfl_xor(sm, off);
            if (mr == 0) {
                const int rw = wm * 64 + i * 16 + rquad + r;
                pm_s[rw][wn] = mx;
                ps_s[rw][wn] = sm;
            }
        }
    }
    __syncthreads();
    if (tid < 128) {
        const float ma = pm_s[tid][0], mb = pm_s[tid][1];
        const float mx = fmaxf(ma, mb);
        const float s  = ps_s[tid][0] * __expf(ma - mx) +
                         ps_s[tid][1] * __expf(mb - mx);
        pmc[tid] = mx;
        Pm[(m0 + tid) * KB + yb] = mx;
        Ps[(m0 + tid) * KB + yb] = s;
    }
    __syncthreads();

    // ---- e16 write: bf16(exp(acc - m_blk)) into upper half of row span -----
    unsigned short* E = (unsigned short*)Mout;
#pragma unroll
    for (int i = 0; i < 4; ++i) {
#pragma unroll
        for (int r = 0; r < 4; ++r) {
            const int rw = wm * 64 + i * 16 + rquad + r;
            const float mx = pmc[rw];
            unsigned short* ep =
                E + (m0 + rw) * 8192L + 4096 + n0 + wn * 64 + col;
#pragma unroll
            for (int j = 0; j < 4; ++j)
                ep[j * 16] = f2bf(__expf(acc[i][j][r] - mx));
        }
    }
}

// ===========================================================================
// Combine per-block softmax partials -> per-row (max, 1/sum) AND rewrite
// Ps in place as CS[n][b] = exp(Pm[n][b] - m_n) * inv_n (av_pv's rescales).
// ===========================================================================
__global__ __launch_bounds__(256)
void finalize_ms(const float* __restrict__ Pm, float* __restrict__ Ps,
                 float* __restrict__ SMm, float* __restrict__ SMi)
{
    const long row = (long)blockIdx.x * 256 + threadIdx.x;
    const float4* pm = (const float4*)(Pm + row * KB);
    float4* ps = (float4*)(Ps + row * KB);
    float4 v[8], w[8];
    float mx = -3.4e38f;
#pragma unroll
    for (int q = 0; q < 8; ++q) {
        v[q] = pm[q];
        w[q] = ps[q];
        mx = fmaxf(mx, fmaxf(fmaxf(v[q].x, v[q].y), fmaxf(v[q].z, v[q].w)));
    }
    float s = 0.f;
#pragma unroll
    for (int q = 0; q < 8; ++q) {
        s += w[q].x * __expf(v[q].x - mx) + w[q].y * __expf(v[q].y - mx) +
             w[q].z * __expf(v[q].z - mx) + w[q].w * __expf(v[q].w - mx);
    }
    const float inv = 1.f / s;
    SMm[row] = mx;
    SMi[row] = inv;
#pragma unroll
    for (int q = 0; q < 8; ++q) {
        float4 c;
        c.x = __expf(v[q].x - mx) * inv;
        c.y = __expf(v[q].y - mx) * inv;
        c.z = __expf(v[q].z - mx) * inv;
        c.w = __expf(v[q].w - mx) * inv;
        ps[q] = c;
    }
}

// ===========================================================================
// Fused softmax-apply + PV from e16 — 2-phase double-buffered pipeline:
//   A[n,k] = bf2f(e16[n,k]) * CS[n][k/128]   (fp32, written over Aout rows)
//   C[n,r] = sum_k A[n,k] * LT[r,k]          (bf16 MFMA, A already normalized)
// Per tile t: {stage Bs[nxt] (t+1), emit As[nxt] (t+1) from prefetched e16,
// prefetch e16(t+2), MFMA(cur)} then ONE barrier. The barrier's vmcnt(0)
// drain lands after a full compute phase instead of right after issue.
// 64 barriers total (was 128). LDS 80 KiB -> 2 blocks/CU (grid 512 = 2/CU).
// Aliasing (A-writes clobber e16 upper half): all e16/A traffic per row is
// thread-private, and every e16 prefetch is reg-resident (drained by the
// iteration barrier) before the emit that clobbers its memory. No guard.
// ===========================================================================
__global__ __launch_bounds__(512, 4)
void softmax_av_pv(float* Aout,                      // NOT restrict: aliases e16
                   const unsigned short* __restrict__ LT,
                   const float* __restrict__ CS,
                   float* __restrict__ C)
{
    __shared__ __align__(16) unsigned short Bs[2][R_DIM * 64]; // 64 KiB (swizzled)
    __shared__ __align__(16) unsigned short As[2][64 * 64];    // 16 KiB (swizzled)

    const int tid  = threadIdx.x;
    const int wave = tid >> 6, lane = tid & 63;
    const long m0 = (long)blockIdx.x * 64;

    const int wm = wave >> 2, wn = wave & 3;  // wave tile: 32 rows x 64 cols
    const int mr = lane & 15;
    const int kq16 = (lane >> 4) * 16;

    // A-emit mapping: each thread owns 2 rows, 4 cols
    const int arow0 = wave * 4 + (lane >> 4);
    const int arow1 = 32 + arow0;
    const int acolE = (lane & 15) * 4;
    const unsigned short* const ep0 =
        (const unsigned short*)Aout + (m0 + arow0) * 8192L + 4096 + acolE;
    const unsigned short* const ep1 =
        (const unsigned short*)Aout + (m0 + arow1) * 8192L + 4096 + acolE;
    float* const gp0 = Aout + (m0 + arow0) * (long)K_DIM + acolE;
    float* const gp1 = Aout + (m0 + arow1) * (long)K_DIM + acolE;
    const int ab0 = (arow0 * 128 + acolE * 2) ^ ((arow0 & 7) << 4);
    const int ab1 = (arow1 * 128 + acolE * 2) ^ ((arow1 & 7) << 4);
    const float* const cs0 = CS + (m0 + arow0) * KB;
    const float* const cs1 = CS + (m0 + arow1) * KB;

    f32x4 acc[2][4] = {};
    constexpr int NT = K_DIM / 64;   // 64 tiles

    // stage LT k-tile into Bs[buf] (source pre-swizzled, dest linear)
    auto stage_B = [&](int buf, int k0) {
#pragma unroll
        for (int q = 0; q < 4; ++q) {
            const int rbase = q * 64 + wave * 8;
            const int rloc  = rbase + (lane >> 3);
            const int phys  = (lane & 7) * 16;
            const int kbyte = phys ^ ((rloc & 7) << 4);
            gl2lds16((const char*)LT + (long)rloc * (K_DIM * 2) + (long)k0 * 2 + kbyte,
                     &Bs[buf][rbase * 64]);
        }
    };
    // emit tile t1 into As[buf] from e16 regs: scale by CS, A-write, LDS bf16
    auto emit_A = [&](int buf, int t1, u16x4 va0, u16x4 va1) {
        const int b  = t1 >> 1;
        const int k0 = t1 * 64;
        const float c0 = cs0[b], c1 = cs1[b];
        float a0 = bf2f(va0[0]) * c0, a1 = bf2f(va0[1]) * c0;
        float a2 = bf2f(va0[2]) * c0, a3 = bf2f(va0[3]) * c0;
        *(float4*)(gp0 + k0) = make_float4(a0, a1, a2, a3);
        u16x4 u0;
        u0[0] = f2bf(a0); u0[1] = f2bf(a1); u0[2] = f2bf(a2); u0[3] = f2bf(a3);
        *(u16x4*)((char*)As[buf] + ab0) = u0;

        float b0 = bf2f(va1[0]) * c1, b1 = bf2f(va1[1]) * c1;
        float b2 = bf2f(va1[2]) * c1, b3 = bf2f(va1[3]) * c1;
        *(float4*)(gp1 + k0) = make_float4(b0, b1, b2, b3);
        u16x4 u1;
        u1[0] = f2bf(b0); u1[1] = f2bf(b1); u1[2] = f2bf(b2); u1[3] = f2bf(b3);
        *(u16x4*)((char*)As[buf] + ab1) = u1;
    };

    // --- prologue: tile 0 staged + emitted; e16(1) prefetched ---------------
    stage_B(0, 0);
    {
        u16x4 e0a = *(const u16x4*)ep0;
        u16x4 e0b = *(const u16x4*)ep1;
        emit_A(0, 0, e0a, e0b);
    }
    u16x4 va0 = *(const u16x4*)(ep0 + 64);   // e16(1)
    u16x4 va1 = *(const u16x4*)(ep1 + 64);
    __syncthreads();

    for (int t = 0; t < NT; ++t) {
        const int cur = t & 1, nxt = cur ^ 1;
        if (t + 1 < NT) {
            stage_B(nxt, (t + 1) * 64);
            emit_A(nxt, t + 1, va0, va1);
        }
        if (t + 2 < NT) {
            va0 = *(const u16x4*)(ep0 + (t + 2) * 64);
            va1 = *(const u16x4*)(ep1 + (t + 2) * 64);
        }

        // ---- MFMA on cur: 2x4 tiles x 2 k-slices ---------------------------
#pragma unroll
        for (int ks = 0; ks < 2; ++ks) {
            bf16x8 af[2], bfr[4];
#pragma unroll
            for (int tt = 0; tt < 2; ++tt) {
                const int ar = wm * 32 + tt * 16 + mr;
                const int ab = (ar * 128 + ks * 64 + kq16) ^ ((ar & 7) << 4);
                af[tt] = *(const bf16x8*)((const char*)As[cur] + ab);
            }
#pragma unroll
            for (int tt = 0; tt < 4; ++tt) {
                const int br = wn * 64 + tt * 16 + mr;
                const int bb = (br * 128 + ks * 64 + kq16) ^ ((br & 7) << 4);
                bfr[tt] = *(const bf16x8*)((const char*)Bs[cur] + bb);
            }
#pragma unroll
            for (int i = 0; i < 2; ++i)
#pragma unroll
                for (int j = 0; j < 4; ++j)
                    acc[i][j] = __builtin_amdgcn_mfma_f32_16x16x32_bf16(
                        af[i], bfr[j], acc[i][j], 0, 0, 0);
        }
        __syncthreads();   // single barrier per tile (drains stage + prefetch)
    }

    // ---- epilogue: A was already normalized -> C = acc directly ------------
    const int col = lane & 15, rquad = (lane >> 4) * 4;
#pragma unroll
    for (int i = 0; i < 2; ++i) {
        const int lrow0 = wm * 32 + i * 16 + rquad;
#pragma unroll
        for (int j = 0; j < 4; ++j) {
            float* p = C + (m0 + lrow0) * (long)R_DIM + wn * 64 + j * 16 + col;
#pragma unroll
            for (int r = 0; r < 4; ++r)
                p[(long)r * R_DIM] = acc[i][j][r];
        }
    }
}

// ===========================================================================
// Prep kernels
// ===========================================================================
// B' = [L_hi | L_lo | L_hi]  (K_DIM x 768)
__global__ __launch_bounds__(256)
void prep_B(const float* __restrict__ L, unsigned short* __restrict__ Bp)
{
    const long i = (long)blockIdx.x * 256 + threadIdx.x;   // over K_DIM*R_DIM
    const long k = i >> 8; const int r = (int)(i & 255);
    const float x = L[i];
    const unsigned short hi = f2bf(x);
    const unsigned short lo = f2bf(x - bf2f(hi));
    unsigned short* row = Bp + k * KP;
    row[r] = hi; row[R_DIM + r] = lo; row[2 * R_DIM + r] = hi;
}

// LT[r][k] = bf16(L[k][r])  (256 x 4096) — coalesced writes
__global__ __launch_bounds__(256)
void prep_LT(const float* __restrict__ L, unsigned short* __restrict__ LT)
{
    const long i = (long)blockIdx.x * 256 + threadIdx.x;   // over R_DIM*K_DIM
    const long r = i >> 12; const long k = i & 4095;
    LT[r * K_DIM + k] = f2bf(L[k * R_DIM + r]);
}

// ===========================================================================
// fp32 VALU GEMM — K1 base + fallback path.
// ===========================================================================
template<bool BT>
__global__ __launch_bounds__(256)
void gemm128(const float* __restrict__ A, const float* __restrict__ B,
             float* __restrict__ C, int M, int N, int Kc)
{
    __shared__ __align__(16) float Asl[16][132];
    __shared__ __align__(16) float Bsl[16][132];

    const int tid = threadIdx.x;
    const int tx = tid & 15, ty = tid >> 4;
    const long m0 = (long)blockIdx.x * 128;
    const long n0 = (long)blockIdx.y * 128;

    float acc[8][8];
#pragma unroll
    for (int i = 0; i < 8; ++i)
#pragma unroll
        for (int j = 0; j < 8; ++j) acc[i][j] = 0.f;

    for (int k0 = 0; k0 < Kc; k0 += 16) {
#pragma unroll
        for (int q = 0; q < 2; ++q) {
            int fi = tid + 256 * q, row = fi >> 2, col = (fi & 3) * 4;
            float4 v = *(const float4*)(A + (m0 + row) * (long)Kc + k0 + col);
            Asl[col + 0][row] = v.x; Asl[col + 1][row] = v.y;
            Asl[col + 2][row] = v.z; Asl[col + 3][row] = v.w;
        }
        if (BT) {
#pragma unroll
            for (int q = 0; q < 2; ++q) {
                int fi = tid + 256 * q, row = fi >> 2, col = (fi & 3) * 4;
                float4 v = *(const float4*)(B + (n0 + row) * (long)Kc + k0 + col);
                Bsl[col + 0][row] = v.x; Bsl[col + 1][row] = v.y;
                Bsl[col + 2][row] = v.z; Bsl[col + 3][row] = v.w;
            }
        } else {
#pragma unroll
            for (int q = 0; q < 2; ++q) {
                int fi = tid + 256 * q, row = fi >> 5, col = (fi & 31) * 4;
                float4 v = *(const float4*)(B + (k0 + row) * (long)N + n0 + col);
                *(float4*)&Bsl[row][col] = v;
            }
        }
        __syncthreads();
#pragma unroll
        for (int kk = 0; kk < 16; ++kk) {
            float a[8], b[8];
            *(float4*)&a[0] = *(const float4*)&Asl[kk][ty * 8];
            *(float4*)&a[4] = *(const float4*)&Asl[kk][ty * 8 + 4];
            *(float4*)&b[0] = *(const float4*)&Bsl[kk][tx * 8];
            *(float4*)&b[4] = *(const float4*)&Bsl[kk][tx * 8 + 4];
#pragma unroll
            for (int i = 0; i < 8; ++i)
#pragma unroll
                for (int j = 0; j < 8; ++j)
                    acc[i][j] = fmaf(a[i], b[j], acc[i][j]);
        }
        __syncthreads();
    }
#pragma unroll
    for (int i = 0; i < 8; ++i) {
        float* p = C + (m0 + ty * 8 + i) * (long)N + n0 + tx * 8;
        *(float4*)p       = make_float4(acc[i][0], acc[i][1], acc[i][2], acc[i][3]);
        *(float4*)(p + 4) = make_float4(acc[i][4], acc[i][5], acc[i][6], acc[i][7]);
    }
}

// ===========================================================================
// K1 with fused split-write: P = A@B (fp32 VALU), epilogue writes
// Ap = [P_hi | P_hi | P_lo] directly (no P materialization).
// ===========================================================================
__global__ __launch_bounds__(256)
void gemm128_hl(const float* __restrict__ A, const float* __restrict__ B,
                unsigned short* __restrict__ Ap, int M, int N, int Kc)
{
    __shared__ __align__(16) float Asl[16][132];
    __shared__ __align__(16) float Bsl[16][132];

    const int tid = threadIdx.x;
    const int tx = tid & 15, ty = tid >> 4;
    const long m0 = (long)blockIdx.x * 128;
    const long n0 = (long)blockIdx.y * 128;

    float acc[8][8];
#pragma unroll
    for (int i = 0; i < 8; ++i)
#pragma unroll
        for (int j = 0; j < 8; ++j) acc[i][j] = 0.f;

    for (int k0 = 0; k0 < Kc; k0 += 16) {
#pragma unroll
        for (int q = 0; q < 2; ++q) {
            int fi = tid + 256 * q, row = fi >> 2, col = (fi & 3) * 4;
            float4 v = *(const float4*)(A + (m0 + row) * (long)Kc + k0 + col);
            Asl[col + 0][row] = v.x; Asl[col + 1][row] = v.y;
            Asl[col + 2][row] = v.z; Asl[col + 3][row] = v.w;
        }
#pragma unroll
        for (int q = 0; q < 2; ++q) {
            int fi = tid + 256 * q, row = fi >> 5, col = (fi & 31) * 4;
            float4 v = *(const float4*)(B + (k0 + row) * (long)N + n0 + col);
            *(float4*)&Bsl[row][col] = v;
        }
        __syncthreads();
#pragma unroll
        for (int kk = 0; kk < 16; ++kk) {
            float a[8], b[8];
            *(float4*)&a[0] = *(const float4*)&Asl[kk][ty * 8];
            *(float4*)&a[4] = *(const float4*)&Asl[kk][ty * 8 + 4];
            *(float4*)&b[0] = *(const float4*)&Bsl[kk][tx * 8];
            *(float4*)&b[4] = *(const float4*)&Bsl[kk][tx * 8 + 4];
#pragma unroll
            for (int i = 0; i < 8; ++i)
#pragma unroll
                for (int j = 0; j < 8; ++j)
                    acc[i][j] = fmaf(a[i], b[j], acc[i][j]);
        }
        __syncthreads();
    }
#pragma unroll
    for (int i = 0; i < 8; ++i) {
        const long row = m0 + ty * 8 + i;
        const int  cb  = (int)n0 + tx * 8;
        u16x8 vh, vl;
#pragma unroll
        for (int j = 0; j < 8; ++j) {
            const float x = acc[i][j];
            const unsigned short hi = f2bf(x);
            vh[j] = hi;
            vl[j] = f2bf(x - bf2f(hi));
        }
        unsigned short* rp = Ap + row * KP;
        *(u16x8*)(rp + cb)             = vh;
        *(u16x8*)(rp + R_DIM + cb)     = vh;
        *(u16x8*)(rp + 2 * R_DIM + cb) = vl;
    }
}

// ---------------------------------------------------------------------------
// In-place row softmax (fallback path only)
// ---------------------------------------------------------------------------
__global__ __launch_bounds__(256)
void softmax_rows(float* __restrict__ Mio)
{
    const long n  = blockIdx.x;
    float* row    = Mio + n * (long)K_DIM;
    const int tid = threadIdx.x;

    float4 v[4];
    float lmax = -3.4e38f;
#pragma unroll
    for (int q = 0; q < 4; ++q) {
        v[q] = ((const float4*)row)[tid + 256 * q];
        lmax = fmaxf(lmax, fmaxf(fmaxf(v[q].x, v[q].y), fmaxf(v[q].z, v[q].w)));
    }
    __shared__ float redmax[4], redsum[4];
#pragma unroll
    for (int off = 32; off > 0; off >>= 1)
        lmax = fmaxf(lmax, __shfl_xor(lmax, off));
    if ((tid & 63) == 0) redmax[tid >> 6] = lmax;
    __syncthreads();
    const float gmax = fmaxf(fmaxf(redmax[0], redmax[1]), fmaxf(redmax[2], redmax[3]));

    float lsum = 0.f;
#pragma unroll
    for (int q = 0; q < 4; ++q) {
        v[q].x = __expf(v[q].x - gmax); v[q].y = __expf(v[q].y - gmax);
        v[q].z = __expf(v[q].z - gmax); v[q].w = __expf(v[q].w - gmax);
        lsum += v[q].x + v[q].y + v[q].z + v[q].w;
    }
#pragma unroll
    for (int off = 32; off > 0; off >>= 1)
        lsum += __shfl_xor(lsum, off);
    if ((tid & 63) == 0) redsum[tid >> 6] = lsum;
    __syncthreads();
    const float inv = 1.f / (redsum[0] + redsum[1] + redsum[2] + redsum[3]);
#pragma unroll
    for (int q = 0; q < 4; ++q) {
        v[q].x *= inv; v[q].y *= inv; v[q].z *= inv; v[q].w *= inv;
        ((float4*)row)[tid + 256 * q] = v[q];
    }
}

// ===========================================================================
extern "C" void kernel_launch(void* const* d_in, const int* in_sizes, int n_in,
                              void* d_out, int out_size, void* d_ws, size_t ws_size,
                              hipStream_t stream)
{
    const float* H  = (const float*)d_in[0];
    const float* L  = (const float*)d_in[1];
    const float* Wi = (const float*)d_in[2];

    float* Cout = (float*)d_out;                           // N x R
    float* Aout = (float*)d_out + (size_t)N_ROWS * R_DIM;  // N x K

    const size_t szAp = (size_t)N_ROWS * KP * 2;    // 48 MiB
    const size_t szBp = (size_t)K_DIM * KP * 2;     //  6 MiB
    const size_t szLT = (size_t)R_DIM * K_DIM * 2;  //  2 MiB
    const size_t szPm = (size_t)N_ROWS * KB * 4;    //  4 MiB
    const size_t szPs = (size_t)N_ROWS * KB * 4;    //  4 MiB
    const size_t szSM = (size_t)N_ROWS * 4;         // 128 KiB

    if (ws_size >= szAp + szBp + szLT + szPm + szPs + 2 * szSM) {
        char* w = (char*)d_ws;
        unsigned short* Ap = (unsigned short*)w;                 w += szAp;
        unsigned short* Bp = (unsigned short*)w;                 w += szBp;
        unsigned short* LT = (unsigned short*)w;                 w += szLT;
        float* Pm  = (float*)w;                                  w += szPm;
        float* Ps  = (float*)w;                                  w += szPs;
        float* SMm = (float*)w;                                  w += szSM;
        float* SMi = (float*)w;

        // K1: P = H@W_I (fp32 VALU), split [hi|hi|lo] written directly to Ap
        gemm128_hl<<<dim3(N_ROWS / 128, R_DIM / 128), 256, 0, stream>>>(
            H, Wi, Ap, N_ROWS, R_DIM, R_DIM);
        // Prep split B operand + transposed bf16 L
        prep_B<<<dim3((K_DIM * R_DIM) / 256), 256, 0, stream>>>(L, Bp);
        prep_LT<<<dim3((R_DIM * K_DIM) / 256), 256, 0, stream>>>(L, LT);
        // K2: logits (3-term split bf16 MFMA) -> e16 + softmax partials
        gemm_mfma_nt<<<dim3((N_ROWS / 128) * (K_DIM / 128)), 256, 0, stream>>>(
            Ap, Bp, Aout, Pm, Ps, N_ROWS, K_DIM, KP);
        // combine partials -> per-row stats; Ps rewritten in place as CS
        finalize_ms<<<dim3(N_ROWS / 256), 256, 0, stream>>>(Pm, Ps, SMm, SMi);
        // fused softmax-apply + PV from e16 (2-phase double-buffered)
        softmax_av_pv<<<dim3(N_ROWS / 64), 512, 0, stream>>>(
            Aout, LT, Ps, Cout);
    } else {
        // Fallback: round-1 fp32 path
        gemm128<false><<<dim3(N_ROWS / 128, R_DIM / 128), 256, 0, stream>>>(
            H, Wi, Cout, N_ROWS, R_DIM, R_DIM);
        gemm128<true><<<dim3(N_ROWS / 128, K_DIM / 128), 256, 0, stream>>>(
            Cout, L, Aout, N_ROWS, K_DIM, R_DIM);
        softmax_rows<<<dim3(N_ROWS), 256, 0, stream>>>(Aout);
        gemm128<false><<<dim3(N_ROWS / 128, R_DIM / 128), 256, 0, stream>>>(
            Aout, L, Cout, N_ROWS, R_DIM, K_DIM);
    }
}